// Round 11
// baseline (701.461 us; speedup 1.0000x reference)
//
#include <hip/hip_runtime.h>
#include <hip/hip_bf16.h>
#include <stdint.h>

// ---------------------------------------------------------------------------
// MGCNN on MI355X — 2-product f16 MFMA conv + all-f16 MFMA gate kernel.
//
// Number format: B operands dual-level (b = b1 + b2), b1 = (f16)v,
// b2 = (f16)(v - b1) stored UNSCALED. Both products accumulate into ONE
// f32 accumulator:  acc = mfma(a, b1, acc); acc = mfma(a, b2, acc)
//
// R26: fragment-layout h/c + doubled gate occupancy — the untested cell
// of the R22/R24 matrix. R22 (2x grid, old layout) doubled traffic via
// partial-line RFO; R24 (fragment layout, 3 blocks/CU) was null because
// 12 waves/CU is latency-spaced. Combo: all h/c accesses full-line
// (fragment order addr(p,o) = (p>>4)*512 + (o>>2)*64 + (p&15)*4 + (o&3))
// removes the RFO mechanism, so 2 blocks/row (grid 1536) at 6 blocks/CU
// (24.5 KB LDS, launch_bounds(256,6), R22 measured 48 VGPR) can scale
// delivered BW. Check: FETCH/WRITE must stay ~52.5/76 MB (vs R22's 2x).
// GEMMs keep R25's XCD swizzle (434.0 us best).
// ---------------------------------------------------------------------------

#define DIM 768
#define MXK 589824        // 768*768
#define STK 2949120       // 5*768*768

typedef _Float16 f16x8 __attribute__((ext_vector_type(8)));
typedef float f32x4 __attribute__((ext_vector_type(4)));
typedef unsigned short ushort_t;
typedef _Float16 f16_t;

__device__ __forceinline__ float sigm(float v) {
    float e = __expf(-v);
    return __builtin_amdgcn_rcpf(1.0f + e);   // raw v_rcp_f32, ~1 ulp
}
__device__ __forceinline__ void split2h(float f, f16_t& h1, f16_t& h2) {
    h1 = (f16_t)f;
    h2 = (f16_t)(f - (float)h1);   // unscaled residual (shared-acc scheme)
}

// async 16B global->LDS (LDS dest = wave-uniform base + lane*16)
__device__ __forceinline__ void gl_lds16(const f16_t* g, f16_t* l) {
    auto gp = reinterpret_cast<const __attribute__((address_space(1))) uint32_t*>(
        reinterpret_cast<uintptr_t>(g));
    auto lp = reinterpret_cast<__attribute__((address_space(3))) uint32_t*>(
        reinterpret_cast<uintptr_t>(l));
    __builtin_amdgcn_global_load_lds(gp, lp, 16, 0, 0);
}

// ---------------------------------------------------------------------------
// init: T0 = I, T1 = L  ->  f16x2s, Tr stack then Tc stack per level
// ---------------------------------------------------------------------------
__global__ __launch_bounds__(256) void init_split(
    const float* __restrict__ Lrow, const float* __restrict__ Lcol,
    f16_t* __restrict__ S0, f16_t* __restrict__ S1)
{
    int idx = blockIdx.x * 256 + threadIdx.x;
    int p = idx / DIM, m = idx % DIM;
    f16_t eye = (p == m) ? (f16_t)1.0f : (f16_t)0.0f;
    S0[idx] = eye; S1[idx] = (f16_t)0.0f;
    S0[STK + idx] = eye; S1[STK + idx] = (f16_t)0.0f;
    f16_t h1, h2;
    split2h(Lrow[idx], h1, h2);
    S0[MXK + idx] = h1; S1[MXK + idx] = h2;
    split2h(Lcol[idx], h1, h2);
    S0[STK + MXK + idx] = h1; S1[STK + MXK + idx] = h2;
}

// ---------------------------------------------------------------------------
// prep: Wstack f16 [128 R][64 k] and thstack f16 [32 o][32 k=ij]
// (k=25 -> bias row, pairs with the ones-row staged into sC; k>25 -> 0)
// ---------------------------------------------------------------------------
__global__ __launch_bounds__(256) void prep_gate(
    const float* __restrict__ Wf, const float* __restrict__ Wi,
    const float* __restrict__ Wo, const float* __restrict__ Wc,
    const float* __restrict__ Uf, const float* __restrict__ Ui,
    const float* __restrict__ Uo, const float* __restrict__ Uc,
    const float* __restrict__ theta, const float* __restrict__ biasv,
    f16_t* __restrict__ Wstack, f16_t* __restrict__ thstack)
{
    int idx = blockIdx.x * 256 + threadIdx.x;
    if (idx < 8192) {
        int R = idx >> 6, k = idx & 63;
        int g = (R >> 4) & 3, o = (R >> 6) * 16 + (R & 15);
        const float* Wg[4] = {Wf, Wi, Wo, Wc};
        const float* Ug[4] = {Uf, Ui, Uo, Uc};
        float v = (k < 32) ? Wg[g][k * 32 + o] : Ug[g][(k - 32) * 32 + o];
        Wstack[idx] = (f16_t)v;
    } else if (idx < 9216) {
        int t = idx - 8192;
        int o = t >> 5, k = t & 31;
        float v = (k < 25) ? theta[k * 32 + o]
                           : (k == 25 ? biasv[o] : 0.0f);
        thstack[o * 32 + k] = (f16_t)v;
    }
}

// ---------------------------------------------------------------------------
// transpose 768x768 + f16x2s split: xT[q][p] = x[p][q] (dual, B of stage1);
// straight f16 single into XR rows 0..767 (A of stage2, T_0 = I) and into
// Cbf rows 0..767 cols 0..767 (T_0 = I both sides).
// ---------------------------------------------------------------------------
__global__ __launch_bounds__(256) void transpose_cvt2x(
    const float* __restrict__ in, f16_t* __restrict__ o1,
    f16_t* __restrict__ o2, f16_t* __restrict__ xr0,
    f16_t* __restrict__ Cbf)
{
    __shared__ float t[32][33];
    int x = threadIdx.x & 31, y = threadIdx.x >> 5;
    int bx = blockIdx.x * 32, by = blockIdx.y * 32;
#pragma unroll
    for (int r = 0; r < 4; ++r) {
        int p = by + y + 8 * r, q = bx + x;
        size_t oi = (size_t)p * DIM + q;
        float v = in[oi];
        t[y + 8 * r][x] = v;
        f16_t hv = (f16_t)v;
        xr0[oi] = hv;
        Cbf[(size_t)p * 3840 + q] = hv;
    }
    __syncthreads();
#pragma unroll
    for (int r = 0; r < 4; ++r) {
        float v = t[x][y + 8 * r];
        f16_t h1, h2;
        split2h(v, h1, h2);
        size_t o = (size_t)(bx + y + 8 * r) * DIM + by + x;
        o1[o] = h1; o2[o] = h2;
    }
}

// ---------------------------------------------------------------------------
// 2-product f16 MFMA GEMM engine, double-buffered LDS (B-transposed,
// k-contig), 128x96 block, BK=32, 4 waves, wave tile 64x48.
// Shared accumulator (R18): acc[4][3] -> __launch_bounds__(256,4),
// 4 blocks/CU (LDS 160 KiB exactly), single scheduling round at 960 blocks.
// R20: B2 == nullptr -> single-product. R25: XCD-aware bijective block
// swizzle (all launches have nwg%8==0) -> contiguous logical chunk per
// XCD -> A/B panel reuse lands in the private 4MB L2.
// mode 1: f16 single out D1 (ldc) + optional D3 (ld 3840);
// mode 2: cheb T2 (v = 2*acc - P), dual out, dual stack via halfStride;
// mode 3: f16 single out (+coloff), supertile (nbx=32);
// mode 4: batched cheb T3+T4 (offset table; pass S0/S1 bases).
// ---------------------------------------------------------------------------
__global__ __launch_bounds__(256, 4) void gemm_bt_h2(
    const f16_t* __restrict__ A1,
    const f16_t* __restrict__ B1, const f16_t* __restrict__ B2,
    const f16_t* __restrict__ P1, const f16_t* __restrict__ P2,
    f16_t* __restrict__ D1, f16_t* __restrict__ D2, f16_t* __restrict__ D3,
    int K, int ldc, int mode, int nbx, int halfStride, int coloff)
{
    __shared__ __align__(16) f16_t sA[2][128 * 32];       // 2 x 8 KB
    __shared__ __align__(16) f16_t sB[2][2 * 96 * 32];    // 2 x 12 KB

    const int tid = threadIdx.x;
    const bool dual = (B2 != nullptr);

    // XCD-aware bijective swizzle (T1): blocks on one XCD (= blockIdx%8)
    // get a CONTIGUOUS chunk of logical ids, so panel reuse stays in that
    // XCD's private L2 instead of striping across all 8 XCDs.
    int g = blockIdx.x;
    {
        int nwg = gridDim.x;
        if ((nwg & 7) == 0) g = (g & 7) * (nwg >> 3) + (g >> 3);
    }

    int bx, by;
    size_t hoff = 0;
    int aoff = 0, boff = 0, poff = 0, doff = 0;
    if (mode == 3) {
        // supertile: 8 rows x 32 cols share A/B panels -> L2 reuse
        int sup = g >> 8;                   // / (8*32)
        int rows0 = sup * 8;
        int H = 30 - rows0; if (H > 8) H = 8;
        int local = g - rows0 * nbx;
        by = rows0 + local % H;
        bx = local / H;
    } else if (mode == 4) {
        // T3 = 2*L@T2 - T1 (g<96), T4 = 2*T2@T2 - T0 (g>=96); Tr|Tc stacks
        int t34 = g / 96, r = g % 96;
        int stack = r / 48, rr = r % 48;
        by = rr >> 3; bx = rr & 7;
        hoff = (size_t)stack * halfStride;
        if (t34 == 0) { aoff = MXK; boff = 2 * MXK; poff = MXK; doff = 3 * MXK; }
        else          { aoff = 2 * MXK; boff = 2 * MXK; poff = 0; doff = 4 * MXK; }
    } else {
        bx = g % nbx;
        by = g / nbx;
        if (mode == 2 && by >= 6) { by -= 6; hoff = (size_t)halfStride; }
    }
    const int m0 = by * 128, n0 = bx * 96;

    const f16_t* Asrc1 = A1 + hoff + aoff;
    const f16_t* Bsrc1 = B1 + hoff + boff;
    const f16_t* Bsrc2 = dual ? B2 + hoff + boff : nullptr;
    const f16_t* Pq1 = P1 ? P1 + hoff + poff : nullptr;
    const f16_t* Pq2 = P2 ? P2 + hoff + poff : nullptr;
    f16_t* Dq1 = D1 + hoff + doff;
    f16_t* Dq2 = D2 ? D2 + hoff + doff : nullptr;

    const int lane = tid & 63, w4 = tid >> 6;
    const int wm = (w4 & 1) * 64, wn = (w4 >> 1) * 48;
    const int lm = lane & 15, quad = lane >> 4;
    const int psw = (quad ^ ((lm >> 1) & 3)) * 8;

    // A staging: 512 16B-slots (128 rows x 4 chunks), 2 calls
    const f16_t* gApt[2]; int aslot[2];
#pragma unroll
    for (int cc = 0; cc < 2; ++cc) {
        int s = cc * 256 + w4 * 64 + lane;   // 0..511
        int row = s >> 2, pos = s & 3;
        int chunk = pos ^ ((row >> 1) & 3);
        gApt[cc] = Asrc1 + (size_t)(m0 + row) * K + chunk * 8;
        aslot[cc] = s * 8;
    }
    // B staging: dual = 768 slots (2 lev x 96 rows x 4 chunks), 3 calls;
    // single = 384 slots (lev 0 only): cc=0 full, cc=1 first 2 waves, cc=2 off
    const f16_t* gBpt[3]; int bslot[3]; bool bact[3];
#pragma unroll
    for (int cc = 0; cc < 3; ++cc) {
        int slot = cc * 256 + w4 * 64 + lane;
        bact[cc] = dual || (slot < 384);
        int lev = slot >= 384 ? 1 : 0;
        int s = slot - lev * 384;
        int row = s >> 2, pos = s & 3;
        int chunk = pos ^ ((row >> 1) & 3);
        const f16_t* bs = (lev && dual) ? Bsrc2 : Bsrc1;
        gBpt[cc] = bs + (size_t)(n0 + row) * K + chunk * 8;
        bslot[cc] = lev * 3072 + s * 8;
    }

    f32x4 acc[4][3] = {};

    // preload K-chunk 0 into buffer 0
#pragma unroll
    for (int cc = 0; cc < 2; ++cc) gl_lds16(gApt[cc], &sA[0][aslot[cc]]);
#pragma unroll
    for (int cc = 0; cc < 3; ++cc)
        if (bact[cc]) gl_lds16(gBpt[cc], &sB[0][bslot[cc]]);
    __syncthreads();

    int ib = 0;
    for (int kb = 0; kb < K; kb += 32, ib ^= 1) {
        // prefetch next chunk into the other buffer (overlaps MFMA below)
        if (kb + 32 < K) {
            int nb = ib ^ 1;
#pragma unroll
            for (int cc = 0; cc < 2; ++cc)
                gl_lds16(gApt[cc] + kb + 32, &sA[nb][aslot[cc]]);
#pragma unroll
            for (int cc = 0; cc < 3; ++cc)
                if (bact[cc]) gl_lds16(gBpt[cc] + kb + 32, &sB[nb][bslot[cc]]);
        }

        f16x8 bfr[2][3];
#pragma unroll
        for (int fn = 0; fn < 3; ++fn)
            bfr[0][fn] = *(const f16x8*)&sB[ib][(wn + fn * 16 + lm) * 32 + psw];
        if (dual) {
#pragma unroll
            for (int fn = 0; fn < 3; ++fn)
                bfr[1][fn] = *(const f16x8*)&sB[ib][3072 +
                                                (wn + fn * 16 + lm) * 32 + psw];
        }
#pragma unroll
        for (int fm = 0; fm < 4; ++fm) {
            f16x8 a1v = *(const f16x8*)&sA[ib][(wm + fm * 16 + lm) * 32 + psw];
#pragma unroll
            for (int fn = 0; fn < 3; ++fn) {
                acc[fm][fn] = __builtin_amdgcn_mfma_f32_16x16x32_f16(
                    a1v, bfr[0][fn], acc[fm][fn], 0, 0, 0);
                if (dual)
                    acc[fm][fn] = __builtin_amdgcn_mfma_f32_16x16x32_f16(
                        a1v, bfr[1][fn], acc[fm][fn], 0, 0, 0);
            }
        }
        // barrier: (a) all waves done reading buf ib (safe to overwrite at
        // kb+64), (b) vmcnt(0) drain -> buf ib^1 staged (loads overlapped
        // the MFMA section above)
        __syncthreads();
    }

    // epilogue: C/D layout col=lane&15, row=quad*4+reg  [verified m89/m91]
#pragma unroll
    for (int fm = 0; fm < 4; ++fm)
#pragma unroll
        for (int fn = 0; fn < 3; ++fn) {
            int col = n0 + wn + fn * 16 + lm;
#pragma unroll
            for (int r = 0; r < 4; ++r) {
                int row = m0 + wm + fm * 16 + quad * 4 + r;
                float val = acc[fm][fn][r];
                if (mode == 3) {
                    Dq1[(size_t)row * ldc + coloff + col] = (f16_t)val;
                } else if (mode == 1) {
                    Dq1[(size_t)row * ldc + col] = (f16_t)val;
                    if (D3) D3[(size_t)row * 3840 + col] = (f16_t)val;
                } else {
                    size_t o = (size_t)row * ldc + col;
                    val = 2.0f * val - ((float)Pq1[o] + (float)Pq2[o]);
                    f16_t h1, h2;
                    split2h(val, h1, h2);
                    Dq1[o] = h1; Dq2[o] = h2;
                }
            }
        }
}

// ---------------------------------------------------------------------------
// Gate kernel (all f16). R26: TWO blocks per row m (grid 1536, 3 tiles
// each), 24.5 KB LDS (sC dbuf 13K + sB 10K + red 1K), launch_bounds
// (256,6) -> 6 blocks/CU, 24 waves/CU, single round. Fragment-layout h/c:
//   addr(p,o) = (p>>4)*512 + (o>>2)*64 + (p&15)*4 + (o&3)
// -> every h/c access is full-64B-line (removes R22's RFO traffic
// amplification at high occupancy). 2-barrier/tile schedule.
// ---------------------------------------------------------------------------
__global__ __launch_bounds__(256, 6) void gate_theta_mfma(
    const f16_t* __restrict__ Cbf, const f16_t* __restrict__ thstack,
    const f16_t* __restrict__ Wstack,
    const float* __restrict__ bfv, const float* __restrict__ biv,
    const float* __restrict__ bov, const float* __restrict__ bcv,
    const float* __restrict__ Wout, const float* __restrict__ bout,
    f16_t* __restrict__ h, f16_t* __restrict__ c, float* __restrict__ x,
    int first, int last)
{
    __shared__ __align__(16) ushort_t sC[2][26 * 128];  // 13 KB dbuf
    __shared__ __align__(16) ushort_t sB[128 * 40];     // 10 KB
    __shared__ float red[256];                          // 1 KB

    const int tid = threadIdx.x;
    const int lane = tid & 63, w4 = tid >> 6;
    const int wm = (w4 & 1) * 64, wn = (w4 >> 1) * 64;
    const int lm = lane & 15, quad = lane >> 4;
    const int m = blockIdx.x >> 1;
    const int colbase = (blockIdx.x & 1) * 384;
    const int o0 = (wm >> 2) + quad * 4;
    const int pw = w4 * 32;
    const size_t ogOff = (size_t)(o0 >> 2) * 64;   // fragment o-group offset

    // ones rows (bias-via-MFMA) once into both buffers
    if (tid < 32) {
        uint4 ones;
        ones.x = ones.y = ones.z = ones.w = 0x3C003C00u;  // f16 1.0 x2
        *(uint4*)&sC[tid >> 4][25 * 128 + (tid & 15) * 8] = ones;
    }

    // stage tile t (local 0..2) -> sC[buf] rows 0..24 (async, 400 x 16B)
    auto stage = [&](int t, int buf) {
        int n0 = colbase + t * 128;
#pragma unroll
        for (int cc = 0; cc < 2; ++cc) {
            int s = cc * 256 + tid;
            if (s < 400) {
                int ij = s >> 4, f = s & 15;
                int i5 = (ij * 205) >> 10;       // ij/5 for ij<32
                int j5 = ij - i5 * 5;
                size_t ga = (size_t)(i5 * DIM + m) * 3840 + j5 * DIM + n0 + f * 8;
                gl_lds16(&Cbf[ga], (f16_t*)&sC[buf][ij * 128 + f * 8]);
            }
        }
    };

    // uniform operands, once per block
    f16x8 bth[2];
#pragma unroll
    for (int fn = 0; fn < 2; ++fn)
        bth[fn] = *(const f16x8*)&thstack[(fn * 16 + lm) * 32 + quad * 8];
    f16x8 af[4][2];
#pragma unroll
    for (int fm = 0; fm < 4; ++fm)
#pragma unroll
        for (int kc = 0; kc < 2; ++kc)
            af[fm][kc] = *(const f16x8*)&Wstack[(wm + fm * 16 + lm) * 64 +
                                                kc * 32 + quad * 8];
    const float4 bgf = *(const float4*)&bfv[o0];
    const float4 bgi = *(const float4*)&biv[o0];
    const float4 bgo = *(const float4*)&bov[o0];
    const float4 bgc = *(const float4*)&bcv[o0];
    const float4 wo4 = *(const float4*)&Wout[o0];
    float bf4[4] = {bgf.x, bgf.y, bgf.z, bgf.w};
    float bi4[4] = {bgi.x, bgi.y, bgi.z, bgi.w};
    float bo4[4] = {bgo.x, bgo.y, bgo.z, bgo.w};
    float bc4[4] = {bgc.x, bgc.y, bgc.z, bgc.w};
    float wo[4] = {wo4.x, wo4.y, wo4.z, wo4.w};
    const float bout0 = bout[0];

    // prologue: stage tiles 0 and 1
    stage(0, 0);
    stage(1, 1);
    __syncthreads();   // ones + tiles 0,1 staged

    for (int t = 0; t < 3; ++t) {
        const int tb = t & 1;
        const int pbase = m * DIM + colbase + t * 128;

        // ---- theta: xc = Cbf-tile^T x theta (+bias via ones row) -> sB ----
        {
            const f16_t* sCf = (const f16_t*)sC[tb];
            f32x4 tacc[2][2] = {};
            f16x8 a0, a1;
#pragma unroll
            for (int j = 0; j < 8; ++j) {
                int k = quad * 8 + j;
                int ij = k > 25 ? 25 : k;   // k>25 hits ones row x thstack 0
                a0[j] = sCf[ij * 128 + pw + lm];
                a1[j] = sCf[ij * 128 + pw + 16 + lm];
            }
#pragma unroll
            for (int fn = 0; fn < 2; ++fn) {
                tacc[0][fn] = __builtin_amdgcn_mfma_f32_16x16x32_f16(
                    a0, bth[fn], tacc[0][fn], 0, 0, 0);
                tacc[1][fn] = __builtin_amdgcn_mfma_f32_16x16x32_f16(
                    a1, bth[fn], tacc[1][fn], 0, 0, 0);
            }
#pragma unroll
            for (int fm2 = 0; fm2 < 2; ++fm2)
#pragma unroll
                for (int fn = 0; fn < 2; ++fn)
#pragma unroll
                    for (int r = 0; r < 4; ++r) {
                        f16_t hv = (f16_t)tacc[fm2][fn][r];
                        sB[(pw + fm2 * 16 + quad * 4 + r) * 40 +
                           fn * 16 + lm] = __builtin_bit_cast(ushort_t, hv);
                    }
        }
        __syncthreads();   // sB visible (also drains any staging leftovers)

        // ---- gate phase ----
        // stage tile 2 into sC[0] during gate(0): read by theta(2), with
        // two barriers in between (drained at the end-of-gate barrier)
        if (t == 0) stage(2, 0);

        // h/c for this tile: fragment layout, full-line wave-contiguous
        f16x8 hfr[4];
        f16_t cold[4][4];
        if (!first) {
#pragma unroll
            for (int fn = 0; fn < 4; ++fn) {
                size_t p = (size_t)(pbase + wn + fn * 16 + lm);
                size_t fb = (p >> 4) * 512 + (size_t)(p & 15) * 4;
                uint2 l0 = *(const uint2*)&h[fb + (size_t)(quad * 2) * 64];
                uint2 l1 = *(const uint2*)&h[fb + (size_t)(quad * 2 + 1) * 64];
                uint4 hv; hv.x = l0.x; hv.y = l0.y; hv.z = l1.x; hv.w = l1.y;
                hfr[fn] = __builtin_bit_cast(f16x8, hv);
                *(uint2*)cold[fn] = *(const uint2*)&c[fb + ogOff];
            }
        } else {
#pragma unroll
            for (int fn = 0; fn < 4; ++fn) {
#pragma unroll
                for (int j = 0; j < 8; ++j) hfr[fn][j] = (f16_t)0.0f;
#pragma unroll
                for (int r = 0; r < 4; ++r) cold[fn][r] = (f16_t)0.0f;
            }
        }

#pragma unroll
        for (int fn = 0; fn < 4; ++fn) {
            f16x8 bxc = *(const f16x8*)&sB[(wn + fn * 16 + lm) * 40 +
                                           quad * 8];
            f32x4 acc[4] = {};
#pragma unroll
            for (int fm = 0; fm < 4; ++fm) {
                acc[fm] = __builtin_amdgcn_mfma_f32_16x16x32_f16(
                    af[fm][0], bxc, acc[fm], 0, 0, 0);
                acc[fm] = __builtin_amdgcn_mfma_f32_16x16x32_f16(
                    af[fm][1], hfr[fn], acc[fm], 0, 0, 0);
            }

            int px = wn + fn * 16 + lm;
            size_t p = (size_t)(pbase + px);
            size_t fb = (p >> 4) * 512 + (size_t)(p & 15) * 4;
            f16_t cn16[4], hn16[4];
            float part = 0.f;
#pragma unroll
            for (int r = 0; r < 4; ++r) {
                float fg = sigm(acc[0][r] + bf4[r]);
                float ig = sigm(acc[1][r] + bi4[r]);
                float og = sigm(acc[2][r] + bo4[r]);
                float gg = sigm(acc[3][r] + bc4[r]);
                float cn = fg * (float)cold[fn][r] + ig * gg;
                cn16[r] = (f16_t)cn;
                hn16[r] = (f16_t)(og * sigm(cn));
                part = fmaf(cn, wo[r], part);
            }
            if (!last) {
                *(uint2*)&c[fb + ogOff] = *(const uint2*)cn16;
                *(uint2*)&h[fb + ogOff] = *(const uint2*)hn16;
            }
            part += __shfl_xor(part, 16, 64);
            part += __shfl_xor(part, 32, 64);
            if (quad == 0) red[px * 2 + (wm >> 6)] = part;
        }
        __syncthreads();   // red visible; tile-2 staging drained

        // ---- x-tail (red has no writer until after the next barrier) ----
        if (tid < 128) {
            float v = red[tid * 2] + red[tid * 2 + 1] + bout0;
            v = fminf(fmaxf(v, -15.f), 15.f);
            float e = __expf(2.f * v);
            x[pbase + tid] += (e - 1.f) * __builtin_amdgcn_rcpf(e + 1.f);
        }
    }
}

// ---------------------------------------------------------------------------
extern "C" void kernel_launch(void* const* d_in, const int* in_sizes, int n_in,
                              void* d_out, int out_size, void* d_ws, size_t ws_size,
                              hipStream_t stream)
{
    const float* x_in  = (const float*)d_in[0];
    const float* Lrow  = (const float*)d_in[1];
    const float* Lcol  = (const float*)d_in[2];
    const float* theta = (const float*)d_in[3];
    const float* bias  = (const float*)d_in[4];
    const float* Wf = (const float*)d_in[5];
    const float* Uf = (const float*)d_in[6];
    const float* bf = (const float*)d_in[7];
    const float* Wi = (const float*)d_in[8];
    const float* Ui = (const float*)d_in[9];
    const float* bi = (const float*)d_in[10];
    const float* Wo = (const float*)d_in[11];
    const float* Uo = (const float*)d_in[12];
    const float* bo = (const float*)d_in[13];
    const float* Wc = (const float*)d_in[14];
    const float* Uc = (const float*)d_in[15];
    const float* bc = (const float*)d_in[16];
    const float* Wout = (const float*)d_in[17];
    const float* bout = (const float*)d_in[18];
    (void)in_sizes; (void)n_in; (void)out_size;

    float* out = (float*)d_out;   // working x buffer

    // ---- workspace pool (136.9 MB) ----
    f16_t* base = (f16_t*)d_ws;
    f16_t* Cbf  = base;                              // 14,745,600 f16
    f16_t* h    = Cbf + 14745600;                    // 18,874,368 f16
    f16_t* c    = h + 18874368;                      // 18,874,368 f16
    f16_t* S0   = c + 18874368;                      // 2*STK (Tr | Tc)
    f16_t* S1   = S0 + 2 * STK;
    f16_t* XR0  = S1 + 2 * STK;                      // STK (single level)
    f16_t* Wstack  = XR0 + STK;                      // 8192
    f16_t* thstack = Wstack + 8192;                  // 1024
    f16_t* xT0  = thstack + 1024;                    // MXK
    f16_t* xT1  = xT0 + MXK;                         // MXK
    if (ws_size < (size_t)136857600) return;

    hipMemcpyAsync(out, x_in, (size_t)MXK * 4, hipMemcpyDeviceToDevice, stream);

    prep_gate<<<36, 256, 0, stream>>>(Wf, Wi, Wo, Wc, Uf, Ui, Uo, Uc, theta,
                                      bias, Wstack, thstack);
    init_split<<<MXK / 256, 256, 0, stream>>>(Lrow, Lcol, S0, S1);
    // T2 = 2*L@L - T0 (Tr+Tc dual stack): A = L hi, B = L dual
    gemm_bt_h2<<<96, 256, 0, stream>>>(
        S0 + MXK, S0 + MXK, S1 + MXK, S0, S1,
        S0 + 2 * MXK, S1 + 2 * MXK, nullptr,
        DIM, DIM, 2, 8, STK, 0);
    // T3 = 2*L@T2 - T1  AND  T4 = 2*T2@T2 - T0, both stacks, one launch
    gemm_bt_h2<<<192, 256, 0, stream>>>(
        S0, S0, S1, S0, S1, S0, S1, nullptr,
        DIM, DIM, 4, 8, STK, 0);

    for (int it = 0; it < 3; ++it) {
        // xT dual split + x f16 into XR rows 0..767 + Cbf rows 0..767 (j0)
        transpose_cvt2x<<<dim3(24, 24), 256, 0, stream>>>(out, xT0, xT1,
                                                          XR0, Cbf);
        // stage1: XR rows 768..3839 = T_{1..4} @ x (f16 single out, dual B);
        // also Cbf j0 rows 768+
        gemm_bt_h2<<<192, 256, 0, stream>>>(
            S0 + MXK, xT0, xT1,
            nullptr, nullptr,
            XR0 + MXK, nullptr, Cbf + (size_t)DIM * 3840,
            DIM, DIM, 1, 8, 0, 0);
        // stage2: Cbf cols 768.. = XR @ Tc_{1..4}^T (M=3840, N=3072, K=768)
        // single-product (B2 = nullptr): A is f16-rounded and D stored f16,
        // so the B residual term is below existing rounding error
        gemm_bt_h2<<<960, 256, 0, stream>>>(
            XR0, S0 + STK + MXK, nullptr,
            nullptr, nullptr,
            Cbf, nullptr, nullptr, DIM, 3840, 3, 32, 0, DIM);
        // gates: theta-MFMA + gate-MFMA + LSTM + x += tanh(c.Wout+b)
        gate_theta_mfma<<<1536, 256, 0, stream>>>(
            Cbf, thstack, Wstack,
            bf, bi, bo, bc, Wout, bout, h, c, out,
            it == 0 ? 1 : 0, it == 2 ? 1 : 0);
    }
}

// Round 12
// 465.774 us; speedup vs baseline: 1.5060x; 1.5060x over previous
//
#include <hip/hip_runtime.h>
#include <hip/hip_bf16.h>
#include <stdint.h>

// ---------------------------------------------------------------------------
// MGCNN on MI355X — 2-product f16 MFMA conv + all-f16 MFMA gate kernel.
//
// Number format: B operands dual-level (b = b1 + b2), b1 = (f16)v,
// b2 = (f16)(v - b1) stored UNSCALED. Both products accumulate into ONE
// f32 accumulator:  acc = mfma(a, b1, acc); acc = mfma(a, b2, acc)
//
// R27: the CLEAN occupancy experiment. R26's launch_bounds(256,6) forced
// VGPR 84->40 -> scratch spill (it=0 FETCH 327 MB vs 28 ideal; spill, not
// RFO — R22's (256,5)/48-VGPR anomaly was the same artifact). Yet R26
// delivered 4.1 TB/s at 61% occupancy — proof the 2.88 TB/s plateau WAS
// concurrency-limited. Now: same grid 1536 / 24.5 KB LDS / fragment-
// layout h/c, but launch_bounds(256,4) (cap 128, kernel wants ~84, no
// spill) -> natural 6 blocks/CU. Spill check: FETCH must return to
// ~52.5 MB, WRITE ~76 MB. GEMMs keep R25's XCD swizzle.
// ---------------------------------------------------------------------------

#define DIM 768
#define MXK 589824        // 768*768
#define STK 2949120       // 5*768*768

typedef _Float16 f16x8 __attribute__((ext_vector_type(8)));
typedef float f32x4 __attribute__((ext_vector_type(4)));
typedef unsigned short ushort_t;
typedef _Float16 f16_t;

__device__ __forceinline__ float sigm(float v) {
    float e = __expf(-v);
    return __builtin_amdgcn_rcpf(1.0f + e);   // raw v_rcp_f32, ~1 ulp
}
__device__ __forceinline__ void split2h(float f, f16_t& h1, f16_t& h2) {
    h1 = (f16_t)f;
    h2 = (f16_t)(f - (float)h1);   // unscaled residual (shared-acc scheme)
}

// async 16B global->LDS (LDS dest = wave-uniform base + lane*16)
__device__ __forceinline__ void gl_lds16(const f16_t* g, f16_t* l) {
    auto gp = reinterpret_cast<const __attribute__((address_space(1))) uint32_t*>(
        reinterpret_cast<uintptr_t>(g));
    auto lp = reinterpret_cast<__attribute__((address_space(3))) uint32_t*>(
        reinterpret_cast<uintptr_t>(l));
    __builtin_amdgcn_global_load_lds(gp, lp, 16, 0, 0);
}

// ---------------------------------------------------------------------------
// init: T0 = I, T1 = L  ->  f16x2s, Tr stack then Tc stack per level
// ---------------------------------------------------------------------------
__global__ __launch_bounds__(256) void init_split(
    const float* __restrict__ Lrow, const float* __restrict__ Lcol,
    f16_t* __restrict__ S0, f16_t* __restrict__ S1)
{
    int idx = blockIdx.x * 256 + threadIdx.x;
    int p = idx / DIM, m = idx % DIM;
    f16_t eye = (p == m) ? (f16_t)1.0f : (f16_t)0.0f;
    S0[idx] = eye; S1[idx] = (f16_t)0.0f;
    S0[STK + idx] = eye; S1[STK + idx] = (f16_t)0.0f;
    f16_t h1, h2;
    split2h(Lrow[idx], h1, h2);
    S0[MXK + idx] = h1; S1[MXK + idx] = h2;
    split2h(Lcol[idx], h1, h2);
    S0[STK + MXK + idx] = h1; S1[STK + MXK + idx] = h2;
}

// ---------------------------------------------------------------------------
// prep: Wstack f16 [128 R][64 k] and thstack f16 [32 o][32 k=ij]
// (k=25 -> bias row, pairs with the ones-row staged into sC; k>25 -> 0)
// ---------------------------------------------------------------------------
__global__ __launch_bounds__(256) void prep_gate(
    const float* __restrict__ Wf, const float* __restrict__ Wi,
    const float* __restrict__ Wo, const float* __restrict__ Wc,
    const float* __restrict__ Uf, const float* __restrict__ Ui,
    const float* __restrict__ Uo, const float* __restrict__ Uc,
    const float* __restrict__ theta, const float* __restrict__ biasv,
    f16_t* __restrict__ Wstack, f16_t* __restrict__ thstack)
{
    int idx = blockIdx.x * 256 + threadIdx.x;
    if (idx < 8192) {
        int R = idx >> 6, k = idx & 63;
        int g = (R >> 4) & 3, o = (R >> 6) * 16 + (R & 15);
        const float* Wg[4] = {Wf, Wi, Wo, Wc};
        const float* Ug[4] = {Uf, Ui, Uo, Uc};
        float v = (k < 32) ? Wg[g][k * 32 + o] : Ug[g][(k - 32) * 32 + o];
        Wstack[idx] = (f16_t)v;
    } else if (idx < 9216) {
        int t = idx - 8192;
        int o = t >> 5, k = t & 31;
        float v = (k < 25) ? theta[k * 32 + o]
                           : (k == 25 ? biasv[o] : 0.0f);
        thstack[o * 32 + k] = (f16_t)v;
    }
}

// ---------------------------------------------------------------------------
// transpose 768x768 + f16x2s split: xT[q][p] = x[p][q] (dual, B of stage1);
// straight f16 single into XR rows 0..767 (A of stage2, T_0 = I) and into
// Cbf rows 0..767 cols 0..767 (T_0 = I both sides).
// ---------------------------------------------------------------------------
__global__ __launch_bounds__(256) void transpose_cvt2x(
    const float* __restrict__ in, f16_t* __restrict__ o1,
    f16_t* __restrict__ o2, f16_t* __restrict__ xr0,
    f16_t* __restrict__ Cbf)
{
    __shared__ float t[32][33];
    int x = threadIdx.x & 31, y = threadIdx.x >> 5;
    int bx = blockIdx.x * 32, by = blockIdx.y * 32;
#pragma unroll
    for (int r = 0; r < 4; ++r) {
        int p = by + y + 8 * r, q = bx + x;
        size_t oi = (size_t)p * DIM + q;
        float v = in[oi];
        t[y + 8 * r][x] = v;
        f16_t hv = (f16_t)v;
        xr0[oi] = hv;
        Cbf[(size_t)p * 3840 + q] = hv;
    }
    __syncthreads();
#pragma unroll
    for (int r = 0; r < 4; ++r) {
        float v = t[x][y + 8 * r];
        f16_t h1, h2;
        split2h(v, h1, h2);
        size_t o = (size_t)(bx + y + 8 * r) * DIM + by + x;
        o1[o] = h1; o2[o] = h2;
    }
}

// ---------------------------------------------------------------------------
// 2-product f16 MFMA GEMM engine, double-buffered LDS (B-transposed,
// k-contig), 128x96 block, BK=32, 4 waves, wave tile 64x48.
// Shared accumulator (R18): acc[4][3] -> __launch_bounds__(256,4),
// 4 blocks/CU (LDS 160 KiB exactly), single scheduling round at 960 blocks.
// R20: B2 == nullptr -> single-product. R25: XCD-aware bijective block
// swizzle (all launches have nwg%8==0) -> contiguous logical chunk per
// XCD -> A/B panel reuse lands in the private 4MB L2.
// mode 1: f16 single out D1 (ldc) + optional D3 (ld 3840);
// mode 2: cheb T2 (v = 2*acc - P), dual out, dual stack via halfStride;
// mode 3: f16 single out (+coloff), supertile (nbx=32);
// mode 4: batched cheb T3+T4 (offset table; pass S0/S1 bases).
// ---------------------------------------------------------------------------
__global__ __launch_bounds__(256, 4) void gemm_bt_h2(
    const f16_t* __restrict__ A1,
    const f16_t* __restrict__ B1, const f16_t* __restrict__ B2,
    const f16_t* __restrict__ P1, const f16_t* __restrict__ P2,
    f16_t* __restrict__ D1, f16_t* __restrict__ D2, f16_t* __restrict__ D3,
    int K, int ldc, int mode, int nbx, int halfStride, int coloff)
{
    __shared__ __align__(16) f16_t sA[2][128 * 32];       // 2 x 8 KB
    __shared__ __align__(16) f16_t sB[2][2 * 96 * 32];    // 2 x 12 KB

    const int tid = threadIdx.x;
    const bool dual = (B2 != nullptr);

    // XCD-aware bijective swizzle (T1): blocks on one XCD (= blockIdx%8)
    // get a CONTIGUOUS chunk of logical ids, so panel reuse stays in that
    // XCD's private L2 instead of striping across all 8 XCDs.
    int g = blockIdx.x;
    {
        int nwg = gridDim.x;
        if ((nwg & 7) == 0) g = (g & 7) * (nwg >> 3) + (g >> 3);
    }

    int bx, by;
    size_t hoff = 0;
    int aoff = 0, boff = 0, poff = 0, doff = 0;
    if (mode == 3) {
        // supertile: 8 rows x 32 cols share A/B panels -> L2 reuse
        int sup = g >> 8;                   // / (8*32)
        int rows0 = sup * 8;
        int H = 30 - rows0; if (H > 8) H = 8;
        int local = g - rows0 * nbx;
        by = rows0 + local % H;
        bx = local / H;
    } else if (mode == 4) {
        // T3 = 2*L@T2 - T1 (g<96), T4 = 2*T2@T2 - T0 (g>=96); Tr|Tc stacks
        int t34 = g / 96, r = g % 96;
        int stack = r / 48, rr = r % 48;
        by = rr >> 3; bx = rr & 7;
        hoff = (size_t)stack * halfStride;
        if (t34 == 0) { aoff = MXK; boff = 2 * MXK; poff = MXK; doff = 3 * MXK; }
        else          { aoff = 2 * MXK; boff = 2 * MXK; poff = 0; doff = 4 * MXK; }
    } else {
        bx = g % nbx;
        by = g / nbx;
        if (mode == 2 && by >= 6) { by -= 6; hoff = (size_t)halfStride; }
    }
    const int m0 = by * 128, n0 = bx * 96;

    const f16_t* Asrc1 = A1 + hoff + aoff;
    const f16_t* Bsrc1 = B1 + hoff + boff;
    const f16_t* Bsrc2 = dual ? B2 + hoff + boff : nullptr;
    const f16_t* Pq1 = P1 ? P1 + hoff + poff : nullptr;
    const f16_t* Pq2 = P2 ? P2 + hoff + poff : nullptr;
    f16_t* Dq1 = D1 + hoff + doff;
    f16_t* Dq2 = D2 ? D2 + hoff + doff : nullptr;

    const int lane = tid & 63, w4 = tid >> 6;
    const int wm = (w4 & 1) * 64, wn = (w4 >> 1) * 48;
    const int lm = lane & 15, quad = lane >> 4;
    const int psw = (quad ^ ((lm >> 1) & 3)) * 8;

    // A staging: 512 16B-slots (128 rows x 4 chunks), 2 calls
    const f16_t* gApt[2]; int aslot[2];
#pragma unroll
    for (int cc = 0; cc < 2; ++cc) {
        int s = cc * 256 + w4 * 64 + lane;   // 0..511
        int row = s >> 2, pos = s & 3;
        int chunk = pos ^ ((row >> 1) & 3);
        gApt[cc] = Asrc1 + (size_t)(m0 + row) * K + chunk * 8;
        aslot[cc] = s * 8;
    }
    // B staging: dual = 768 slots (2 lev x 96 rows x 4 chunks), 3 calls;
    // single = 384 slots (lev 0 only): cc=0 full, cc=1 first 2 waves, cc=2 off
    const f16_t* gBpt[3]; int bslot[3]; bool bact[3];
#pragma unroll
    for (int cc = 0; cc < 3; ++cc) {
        int slot = cc * 256 + w4 * 64 + lane;
        bact[cc] = dual || (slot < 384);
        int lev = slot >= 384 ? 1 : 0;
        int s = slot - lev * 384;
        int row = s >> 2, pos = s & 3;
        int chunk = pos ^ ((row >> 1) & 3);
        const f16_t* bs = (lev && dual) ? Bsrc2 : Bsrc1;
        gBpt[cc] = bs + (size_t)(n0 + row) * K + chunk * 8;
        bslot[cc] = lev * 3072 + s * 8;
    }

    f32x4 acc[4][3] = {};

    // preload K-chunk 0 into buffer 0
#pragma unroll
    for (int cc = 0; cc < 2; ++cc) gl_lds16(gApt[cc], &sA[0][aslot[cc]]);
#pragma unroll
    for (int cc = 0; cc < 3; ++cc)
        if (bact[cc]) gl_lds16(gBpt[cc], &sB[0][bslot[cc]]);
    __syncthreads();

    int ib = 0;
    for (int kb = 0; kb < K; kb += 32, ib ^= 1) {
        // prefetch next chunk into the other buffer (overlaps MFMA below)
        if (kb + 32 < K) {
            int nb = ib ^ 1;
#pragma unroll
            for (int cc = 0; cc < 2; ++cc)
                gl_lds16(gApt[cc] + kb + 32, &sA[nb][aslot[cc]]);
#pragma unroll
            for (int cc = 0; cc < 3; ++cc)
                if (bact[cc]) gl_lds16(gBpt[cc] + kb + 32, &sB[nb][bslot[cc]]);
        }

        f16x8 bfr[2][3];
#pragma unroll
        for (int fn = 0; fn < 3; ++fn)
            bfr[0][fn] = *(const f16x8*)&sB[ib][(wn + fn * 16 + lm) * 32 + psw];
        if (dual) {
#pragma unroll
            for (int fn = 0; fn < 3; ++fn)
                bfr[1][fn] = *(const f16x8*)&sB[ib][3072 +
                                                (wn + fn * 16 + lm) * 32 + psw];
        }
#pragma unroll
        for (int fm = 0; fm < 4; ++fm) {
            f16x8 a1v = *(const f16x8*)&sA[ib][(wm + fm * 16 + lm) * 32 + psw];
#pragma unroll
            for (int fn = 0; fn < 3; ++fn) {
                acc[fm][fn] = __builtin_amdgcn_mfma_f32_16x16x32_f16(
                    a1v, bfr[0][fn], acc[fm][fn], 0, 0, 0);
                if (dual)
                    acc[fm][fn] = __builtin_amdgcn_mfma_f32_16x16x32_f16(
                        a1v, bfr[1][fn], acc[fm][fn], 0, 0, 0);
            }
        }
        // barrier: (a) all waves done reading buf ib (safe to overwrite at
        // kb+64), (b) vmcnt(0) drain -> buf ib^1 staged (loads overlapped
        // the MFMA section above)
        __syncthreads();
    }

    // epilogue: C/D layout col=lane&15, row=quad*4+reg  [verified m89/m91]
#pragma unroll
    for (int fm = 0; fm < 4; ++fm)
#pragma unroll
        for (int fn = 0; fn < 3; ++fn) {
            int col = n0 + wn + fn * 16 + lm;
#pragma unroll
            for (int r = 0; r < 4; ++r) {
                int row = m0 + wm + fm * 16 + quad * 4 + r;
                float val = acc[fm][fn][r];
                if (mode == 3) {
                    Dq1[(size_t)row * ldc + coloff + col] = (f16_t)val;
                } else if (mode == 1) {
                    Dq1[(size_t)row * ldc + col] = (f16_t)val;
                    if (D3) D3[(size_t)row * 3840 + col] = (f16_t)val;
                } else {
                    size_t o = (size_t)row * ldc + col;
                    val = 2.0f * val - ((float)Pq1[o] + (float)Pq2[o]);
                    f16_t h1, h2;
                    split2h(val, h1, h2);
                    Dq1[o] = h1; Dq2[o] = h2;
                }
            }
        }
}

// ---------------------------------------------------------------------------
// Gate kernel (all f16). R27: TWO blocks per row m (grid 1536, 3 tiles
// each), 24.5 KB LDS (sC dbuf 13K + sB 10K + red 1K). launch_bounds
// (256,4): cap 128 VGPR >> the kernel's ~84 -> NO SPILL; natural runtime
// occupancy = min(VGPR 6, LDS 6, grid 6) = 6 blocks/CU, 24 waves/CU.
// Fragment-layout h/c (all accesses full-64B-line):
//   addr(p,o) = (p>>4)*512 + (o>>2)*64 + (p&15)*4 + (o&3)
// 2-barrier/tile schedule.
// ---------------------------------------------------------------------------
__global__ __launch_bounds__(256, 4) void gate_theta_mfma(
    const f16_t* __restrict__ Cbf, const f16_t* __restrict__ thstack,
    const f16_t* __restrict__ Wstack,
    const float* __restrict__ bfv, const float* __restrict__ biv,
    const float* __restrict__ bov, const float* __restrict__ bcv,
    const float* __restrict__ Wout, const float* __restrict__ bout,
    f16_t* __restrict__ h, f16_t* __restrict__ c, float* __restrict__ x,
    int first, int last)
{
    __shared__ __align__(16) ushort_t sC[2][26 * 128];  // 13 KB dbuf
    __shared__ __align__(16) ushort_t sB[128 * 40];     // 10 KB
    __shared__ float red[256];                          // 1 KB

    const int tid = threadIdx.x;
    const int lane = tid & 63, w4 = tid >> 6;
    const int wm = (w4 & 1) * 64, wn = (w4 >> 1) * 64;
    const int lm = lane & 15, quad = lane >> 4;
    const int m = blockIdx.x >> 1;
    const int colbase = (blockIdx.x & 1) * 384;
    const int o0 = (wm >> 2) + quad * 4;
    const int pw = w4 * 32;
    const size_t ogOff = (size_t)(o0 >> 2) * 64;   // fragment o-group offset

    // ones rows (bias-via-MFMA) once into both buffers
    if (tid < 32) {
        uint4 ones;
        ones.x = ones.y = ones.z = ones.w = 0x3C003C00u;  // f16 1.0 x2
        *(uint4*)&sC[tid >> 4][25 * 128 + (tid & 15) * 8] = ones;
    }

    // stage tile t (local 0..2) -> sC[buf] rows 0..24 (async, 400 x 16B)
    auto stage = [&](int t, int buf) {
        int n0 = colbase + t * 128;
#pragma unroll
        for (int cc = 0; cc < 2; ++cc) {
            int s = cc * 256 + tid;
            if (s < 400) {
                int ij = s >> 4, f = s & 15;
                int i5 = (ij * 205) >> 10;       // ij/5 for ij<32
                int j5 = ij - i5 * 5;
                size_t ga = (size_t)(i5 * DIM + m) * 3840 + j5 * DIM + n0 + f * 8;
                gl_lds16(&Cbf[ga], (f16_t*)&sC[buf][ij * 128 + f * 8]);
            }
        }
    };

    // uniform operands, once per block
    f16x8 bth[2];
#pragma unroll
    for (int fn = 0; fn < 2; ++fn)
        bth[fn] = *(const f16x8*)&thstack[(fn * 16 + lm) * 32 + quad * 8];
    f16x8 af[4][2];
#pragma unroll
    for (int fm = 0; fm < 4; ++fm)
#pragma unroll
        for (int kc = 0; kc < 2; ++kc)
            af[fm][kc] = *(const f16x8*)&Wstack[(wm + fm * 16 + lm) * 64 +
                                                kc * 32 + quad * 8];
    const float4 bgf = *(const float4*)&bfv[o0];
    const float4 bgi = *(const float4*)&biv[o0];
    const float4 bgo = *(const float4*)&bov[o0];
    const float4 bgc = *(const float4*)&bcv[o0];
    const float4 wo4 = *(const float4*)&Wout[o0];
    float bf4[4] = {bgf.x, bgf.y, bgf.z, bgf.w};
    float bi4[4] = {bgi.x, bgi.y, bgi.z, bgi.w};
    float bo4[4] = {bgo.x, bgo.y, bgo.z, bgo.w};
    float bc4[4] = {bgc.x, bgc.y, bgc.z, bgc.w};
    float wo[4] = {wo4.x, wo4.y, wo4.z, wo4.w};
    const float bout0 = bout[0];

    // prologue: stage tiles 0 and 1
    stage(0, 0);
    stage(1, 1);
    __syncthreads();   // ones + tiles 0,1 staged

    for (int t = 0; t < 3; ++t) {
        const int tb = t & 1;
        const int pbase = m * DIM + colbase + t * 128;

        // ---- theta: xc = Cbf-tile^T x theta (+bias via ones row) -> sB ----
        {
            const f16_t* sCf = (const f16_t*)sC[tb];
            f32x4 tacc[2][2] = {};
            f16x8 a0, a1;
#pragma unroll
            for (int j = 0; j < 8; ++j) {
                int k = quad * 8 + j;
                int ij = k > 25 ? 25 : k;   // k>25 hits ones row x thstack 0
                a0[j] = sCf[ij * 128 + pw + lm];
                a1[j] = sCf[ij * 128 + pw + 16 + lm];
            }
#pragma unroll
            for (int fn = 0; fn < 2; ++fn) {
                tacc[0][fn] = __builtin_amdgcn_mfma_f32_16x16x32_f16(
                    a0, bth[fn], tacc[0][fn], 0, 0, 0);
                tacc[1][fn] = __builtin_amdgcn_mfma_f32_16x16x32_f16(
                    a1, bth[fn], tacc[1][fn], 0, 0, 0);
            }
#pragma unroll
            for (int fm2 = 0; fm2 < 2; ++fm2)
#pragma unroll
                for (int fn = 0; fn < 2; ++fn)
#pragma unroll
                    for (int r = 0; r < 4; ++r) {
                        f16_t hv = (f16_t)tacc[fm2][fn][r];
                        sB[(pw + fm2 * 16 + quad * 4 + r) * 40 +
                           fn * 16 + lm] = __builtin_bit_cast(ushort_t, hv);
                    }
        }
        __syncthreads();   // sB visible (also drains any staging leftovers)

        // ---- gate phase ----
        // stage tile 2 into sC[0] during gate(0): read by theta(2), with
        // two barriers in between (drained at the end-of-gate barrier)
        if (t == 0) stage(2, 0);

        // h/c for this tile: fragment layout, full-line wave-contiguous
        f16x8 hfr[4];
        f16_t cold[4][4];
        if (!first) {
#pragma unroll
            for (int fn = 0; fn < 4; ++fn) {
                size_t p = (size_t)(pbase + wn + fn * 16 + lm);
                size_t fb = (p >> 4) * 512 + (size_t)(p & 15) * 4;
                uint2 l0 = *(const uint2*)&h[fb + (size_t)(quad * 2) * 64];
                uint2 l1 = *(const uint2*)&h[fb + (size_t)(quad * 2 + 1) * 64];
                uint4 hv; hv.x = l0.x; hv.y = l0.y; hv.z = l1.x; hv.w = l1.y;
                hfr[fn] = __builtin_bit_cast(f16x8, hv);
                *(uint2*)cold[fn] = *(const uint2*)&c[fb + ogOff];
            }
        } else {
#pragma unroll
            for (int fn = 0; fn < 4; ++fn) {
#pragma unroll
                for (int j = 0; j < 8; ++j) hfr[fn][j] = (f16_t)0.0f;
#pragma unroll
                for (int r = 0; r < 4; ++r) cold[fn][r] = (f16_t)0.0f;
            }
        }

#pragma unroll
        for (int fn = 0; fn < 4; ++fn) {
            f16x8 bxc = *(const f16x8*)&sB[(wn + fn * 16 + lm) * 40 +
                                           quad * 8];
            f32x4 acc[4] = {};
#pragma unroll
            for (int fm = 0; fm < 4; ++fm) {
                acc[fm] = __builtin_amdgcn_mfma_f32_16x16x32_f16(
                    af[fm][0], bxc, acc[fm], 0, 0, 0);
                acc[fm] = __builtin_amdgcn_mfma_f32_16x16x32_f16(
                    af[fm][1], hfr[fn], acc[fm], 0, 0, 0);
            }

            int px = wn + fn * 16 + lm;
            size_t p = (size_t)(pbase + px);
            size_t fb = (p >> 4) * 512 + (size_t)(p & 15) * 4;
            f16_t cn16[4], hn16[4];
            float part = 0.f;
#pragma unroll
            for (int r = 0; r < 4; ++r) {
                float fg = sigm(acc[0][r] + bf4[r]);
                float ig = sigm(acc[1][r] + bi4[r]);
                float og = sigm(acc[2][r] + bo4[r]);
                float gg = sigm(acc[3][r] + bc4[r]);
                float cn = fg * (float)cold[fn][r] + ig * gg;
                cn16[r] = (f16_t)cn;
                hn16[r] = (f16_t)(og * sigm(cn));
                part = fmaf(cn, wo[r], part);
            }
            if (!last) {
                *(uint2*)&c[fb + ogOff] = *(const uint2*)cn16;
                *(uint2*)&h[fb + ogOff] = *(const uint2*)hn16;
            }
            part += __shfl_xor(part, 16, 64);
            part += __shfl_xor(part, 32, 64);
            if (quad == 0) red[px * 2 + (wm >> 6)] = part;
        }
        __syncthreads();   // red visible; tile-2 staging drained

        // ---- x-tail (red has no writer until after the next barrier) ----
        if (tid < 128) {
            float v = red[tid * 2] + red[tid * 2 + 1] + bout0;
            v = fminf(fmaxf(v, -15.f), 15.f);
            float e = __expf(2.f * v);
            x[pbase + tid] += (e - 1.f) * __builtin_amdgcn_rcpf(e + 1.f);
        }
    }
}

// ---------------------------------------------------------------------------
extern "C" void kernel_launch(void* const* d_in, const int* in_sizes, int n_in,
                              void* d_out, int out_size, void* d_ws, size_t ws_size,
                              hipStream_t stream)
{
    const float* x_in  = (const float*)d_in[0];
    const float* Lrow  = (const float*)d_in[1];
    const float* Lcol  = (const float*)d_in[2];
    const float* theta = (const float*)d_in[3];
    const float* bias  = (const float*)d_in[4];
    const float* Wf = (const float*)d_in[5];
    const float* Uf = (const float*)d_in[6];
    const float* bf = (const float*)d_in[7];
    const float* Wi = (const float*)d_in[8];
    const float* Ui = (const float*)d_in[9];
    const float* bi = (const float*)d_in[10];
    const float* Wo = (const float*)d_in[11];
    const float* Uo = (const float*)d_in[12];
    const float* bo = (const float*)d_in[13];
    const float* Wc = (const float*)d_in[14];
    const float* Uc = (const float*)d_in[15];
    const float* bc = (const float*)d_in[16];
    const float* Wout = (const float*)d_in[17];
    const float* bout = (const float*)d_in[18];
    (void)in_sizes; (void)n_in; (void)out_size;

    float* out = (float*)d_out;   // working x buffer

    // ---- workspace pool (136.9 MB) ----
    f16_t* base = (f16_t*)d_ws;
    f16_t* Cbf  = base;                              // 14,745,600 f16
    f16_t* h    = Cbf + 14745600;                    // 18,874,368 f16
    f16_t* c    = h + 18874368;                      // 18,874,368 f16
    f16_t* S0   = c + 18874368;                      // 2*STK (Tr | Tc)
    f16_t* S1   = S0 + 2 * STK;
    f16_t* XR0  = S1 + 2 * STK;                      // STK (single level)
    f16_t* Wstack  = XR0 + STK;                      // 8192
    f16_t* thstack = Wstack + 8192;                  // 1024
    f16_t* xT0  = thstack + 1024;                    // MXK
    f16_t* xT1  = xT0 + MXK;                         // MXK
    if (ws_size < (size_t)136857600) return;

    hipMemcpyAsync(out, x_in, (size_t)MXK * 4, hipMemcpyDeviceToDevice, stream);

    prep_gate<<<36, 256, 0, stream>>>(Wf, Wi, Wo, Wc, Uf, Ui, Uo, Uc, theta,
                                      bias, Wstack, thstack);
    init_split<<<MXK / 256, 256, 0, stream>>>(Lrow, Lcol, S0, S1);
    // T2 = 2*L@L - T0 (Tr+Tc dual stack): A = L hi, B = L dual
    gemm_bt_h2<<<96, 256, 0, stream>>>(
        S0 + MXK, S0 + MXK, S1 + MXK, S0, S1,
        S0 + 2 * MXK, S1 + 2 * MXK, nullptr,
        DIM, DIM, 2, 8, STK, 0);
    // T3 = 2*L@T2 - T1  AND  T4 = 2*T2@T2 - T0, both stacks, one launch
    gemm_bt_h2<<<192, 256, 0, stream>>>(
        S0, S0, S1, S0, S1, S0, S1, nullptr,
        DIM, DIM, 4, 8, STK, 0);

    for (int it = 0; it < 3; ++it) {
        // xT dual split + x f16 into XR rows 0..767 + Cbf rows 0..767 (j0)
        transpose_cvt2x<<<dim3(24, 24), 256, 0, stream>>>(out, xT0, xT1,
                                                          XR0, Cbf);
        // stage1: XR rows 768..3839 = T_{1..4} @ x (f16 single out, dual B);
        // also Cbf j0 rows 768+
        gemm_bt_h2<<<192, 256, 0, stream>>>(
            S0 + MXK, xT0, xT1,
            nullptr, nullptr,
            XR0 + MXK, nullptr, Cbf + (size_t)DIM * 3840,
            DIM, DIM, 1, 8, 0, 0);
        // stage2: Cbf cols 768.. = XR @ Tc_{1..4}^T (M=3840, N=3072, K=768)
        // single-product (B2 = nullptr): A is f16-rounded and D stored f16,
        // so the B residual term is below existing rounding error
        gemm_bt_h2<<<960, 256, 0, stream>>>(
            XR0, S0 + STK + MXK, nullptr,
            nullptr, nullptr,
            Cbf, nullptr, nullptr, DIM, 3840, 3, 32, 0, DIM);
        // gates: theta-MFMA + gate-MFMA + LSTM + x += tanh(c.Wout+b)
        gate_theta_mfma<<<1536, 256, 0, stream>>>(
            Cbf, thstack, Wstack,
            bf, bi, bo, bc, Wout, bout, h, c, out,
            it == 0 ? 1 : 0, it == 2 ? 1 : 0);
    }
}

// Round 13
// 431.147 us; speedup vs baseline: 1.6270x; 1.0803x over previous
//
#include <hip/hip_runtime.h>
#include <hip/hip_bf16.h>
#include <stdint.h>

// ---------------------------------------------------------------------------
// MGCNN on MI355X — 2-product f16 MFMA conv + all-f16 MFMA gate kernel.
//
// Number format: B operands dual-level (b = b1 + b2), b1 = (f16)v,
// b2 = (f16)(v - b1) stored UNSCALED. Both products accumulate into ONE
// f32 accumulator:  acc = mfma(a, b1, acc); acc = mfma(a, b2, acc)
//
// R28: R27 minus the spill trigger. R27's launch_bounds(256,4) let the
// allocator chase the 64-reg/8-wave boundary -> spill (VGPR 64, FETCH +11,
// WRITE +26 MB, scratch capped occupancy at 30%). Register arithmetic
// (~110 peak demand) says 6 blocks/CU is unreachable; the clean point is
// 4 blocks/CU / 16 waves, which needs the (256,3) cap=170 this kernel has
// always compiled spill-free under (84 regs). Same slim kernel: grid 1536
// (2 blocks/row, 3 tiles), 24.5 KB LDS, fragment-layout h/c (full-line).
// R26 proved the memory system gives 4.1 TB/s with enough waves; this
// buys +33% waves with zero spill risk. GEMMs keep R25's XCD swizzle.
// ---------------------------------------------------------------------------

#define DIM 768
#define MXK 589824        // 768*768
#define STK 2949120       // 5*768*768

typedef _Float16 f16x8 __attribute__((ext_vector_type(8)));
typedef float f32x4 __attribute__((ext_vector_type(4)));
typedef unsigned short ushort_t;
typedef _Float16 f16_t;

__device__ __forceinline__ float sigm(float v) {
    float e = __expf(-v);
    return __builtin_amdgcn_rcpf(1.0f + e);   // raw v_rcp_f32, ~1 ulp
}
__device__ __forceinline__ void split2h(float f, f16_t& h1, f16_t& h2) {
    h1 = (f16_t)f;
    h2 = (f16_t)(f - (float)h1);   // unscaled residual (shared-acc scheme)
}

// async 16B global->LDS (LDS dest = wave-uniform base + lane*16)
__device__ __forceinline__ void gl_lds16(const f16_t* g, f16_t* l) {
    auto gp = reinterpret_cast<const __attribute__((address_space(1))) uint32_t*>(
        reinterpret_cast<uintptr_t>(g));
    auto lp = reinterpret_cast<__attribute__((address_space(3))) uint32_t*>(
        reinterpret_cast<uintptr_t>(l));
    __builtin_amdgcn_global_load_lds(gp, lp, 16, 0, 0);
}

// ---------------------------------------------------------------------------
// init: T0 = I, T1 = L  ->  f16x2s, Tr stack then Tc stack per level
// ---------------------------------------------------------------------------
__global__ __launch_bounds__(256) void init_split(
    const float* __restrict__ Lrow, const float* __restrict__ Lcol,
    f16_t* __restrict__ S0, f16_t* __restrict__ S1)
{
    int idx = blockIdx.x * 256 + threadIdx.x;
    int p = idx / DIM, m = idx % DIM;
    f16_t eye = (p == m) ? (f16_t)1.0f : (f16_t)0.0f;
    S0[idx] = eye; S1[idx] = (f16_t)0.0f;
    S0[STK + idx] = eye; S1[STK + idx] = (f16_t)0.0f;
    f16_t h1, h2;
    split2h(Lrow[idx], h1, h2);
    S0[MXK + idx] = h1; S1[MXK + idx] = h2;
    split2h(Lcol[idx], h1, h2);
    S0[STK + MXK + idx] = h1; S1[STK + MXK + idx] = h2;
}

// ---------------------------------------------------------------------------
// prep: Wstack f16 [128 R][64 k] and thstack f16 [32 o][32 k=ij]
// (k=25 -> bias row, pairs with the ones-row staged into sC; k>25 -> 0)
// ---------------------------------------------------------------------------
__global__ __launch_bounds__(256) void prep_gate(
    const float* __restrict__ Wf, const float* __restrict__ Wi,
    const float* __restrict__ Wo, const float* __restrict__ Wc,
    const float* __restrict__ Uf, const float* __restrict__ Ui,
    const float* __restrict__ Uo, const float* __restrict__ Uc,
    const float* __restrict__ theta, const float* __restrict__ biasv,
    f16_t* __restrict__ Wstack, f16_t* __restrict__ thstack)
{
    int idx = blockIdx.x * 256 + threadIdx.x;
    if (idx < 8192) {
        int R = idx >> 6, k = idx & 63;
        int g = (R >> 4) & 3, o = (R >> 6) * 16 + (R & 15);
        const float* Wg[4] = {Wf, Wi, Wo, Wc};
        const float* Ug[4] = {Uf, Ui, Uo, Uc};
        float v = (k < 32) ? Wg[g][k * 32 + o] : Ug[g][(k - 32) * 32 + o];
        Wstack[idx] = (f16_t)v;
    } else if (idx < 9216) {
        int t = idx - 8192;
        int o = t >> 5, k = t & 31;
        float v = (k < 25) ? theta[k * 32 + o]
                           : (k == 25 ? biasv[o] : 0.0f);
        thstack[o * 32 + k] = (f16_t)v;
    }
}

// ---------------------------------------------------------------------------
// transpose 768x768 + f16x2s split: xT[q][p] = x[p][q] (dual, B of stage1);
// straight f16 single into XR rows 0..767 (A of stage2, T_0 = I) and into
// Cbf rows 0..767 cols 0..767 (T_0 = I both sides).
// ---------------------------------------------------------------------------
__global__ __launch_bounds__(256) void transpose_cvt2x(
    const float* __restrict__ in, f16_t* __restrict__ o1,
    f16_t* __restrict__ o2, f16_t* __restrict__ xr0,
    f16_t* __restrict__ Cbf)
{
    __shared__ float t[32][33];
    int x = threadIdx.x & 31, y = threadIdx.x >> 5;
    int bx = blockIdx.x * 32, by = blockIdx.y * 32;
#pragma unroll
    for (int r = 0; r < 4; ++r) {
        int p = by + y + 8 * r, q = bx + x;
        size_t oi = (size_t)p * DIM + q;
        float v = in[oi];
        t[y + 8 * r][x] = v;
        f16_t hv = (f16_t)v;
        xr0[oi] = hv;
        Cbf[(size_t)p * 3840 + q] = hv;
    }
    __syncthreads();
#pragma unroll
    for (int r = 0; r < 4; ++r) {
        float v = t[x][y + 8 * r];
        f16_t h1, h2;
        split2h(v, h1, h2);
        size_t o = (size_t)(bx + y + 8 * r) * DIM + by + x;
        o1[o] = h1; o2[o] = h2;
    }
}

// ---------------------------------------------------------------------------
// 2-product f16 MFMA GEMM engine, double-buffered LDS (B-transposed,
// k-contig), 128x96 block, BK=32, 4 waves, wave tile 64x48.
// Shared accumulator (R18): acc[4][3] -> __launch_bounds__(256,4),
// 4 blocks/CU (LDS 160 KiB exactly), single scheduling round at 960 blocks.
// R20: B2 == nullptr -> single-product. R25: XCD-aware bijective block
// swizzle (all launches have nwg%8==0) -> contiguous logical chunk per
// XCD -> A/B panel reuse lands in the private 4MB L2.
// mode 1: f16 single out D1 (ldc) + optional D3 (ld 3840);
// mode 2: cheb T2 (v = 2*acc - P), dual out, dual stack via halfStride;
// mode 3: f16 single out (+coloff), supertile (nbx=32);
// mode 4: batched cheb T3+T4 (offset table; pass S0/S1 bases).
// ---------------------------------------------------------------------------
__global__ __launch_bounds__(256, 4) void gemm_bt_h2(
    const f16_t* __restrict__ A1,
    const f16_t* __restrict__ B1, const f16_t* __restrict__ B2,
    const f16_t* __restrict__ P1, const f16_t* __restrict__ P2,
    f16_t* __restrict__ D1, f16_t* __restrict__ D2, f16_t* __restrict__ D3,
    int K, int ldc, int mode, int nbx, int halfStride, int coloff)
{
    __shared__ __align__(16) f16_t sA[2][128 * 32];       // 2 x 8 KB
    __shared__ __align__(16) f16_t sB[2][2 * 96 * 32];    // 2 x 12 KB

    const int tid = threadIdx.x;
    const bool dual = (B2 != nullptr);

    // XCD-aware bijective swizzle (T1): blocks on one XCD (= blockIdx%8)
    // get a CONTIGUOUS chunk of logical ids, so panel reuse stays in that
    // XCD's private L2 instead of striping across all 8 XCDs.
    int g = blockIdx.x;
    {
        int nwg = gridDim.x;
        if ((nwg & 7) == 0) g = (g & 7) * (nwg >> 3) + (g >> 3);
    }

    int bx, by;
    size_t hoff = 0;
    int aoff = 0, boff = 0, poff = 0, doff = 0;
    if (mode == 3) {
        // supertile: 8 rows x 32 cols share A/B panels -> L2 reuse
        int sup = g >> 8;                   // / (8*32)
        int rows0 = sup * 8;
        int H = 30 - rows0; if (H > 8) H = 8;
        int local = g - rows0 * nbx;
        by = rows0 + local % H;
        bx = local / H;
    } else if (mode == 4) {
        // T3 = 2*L@T2 - T1 (g<96), T4 = 2*T2@T2 - T0 (g>=96); Tr|Tc stacks
        int t34 = g / 96, r = g % 96;
        int stack = r / 48, rr = r % 48;
        by = rr >> 3; bx = rr & 7;
        hoff = (size_t)stack * halfStride;
        if (t34 == 0) { aoff = MXK; boff = 2 * MXK; poff = MXK; doff = 3 * MXK; }
        else          { aoff = 2 * MXK; boff = 2 * MXK; poff = 0; doff = 4 * MXK; }
    } else {
        bx = g % nbx;
        by = g / nbx;
        if (mode == 2 && by >= 6) { by -= 6; hoff = (size_t)halfStride; }
    }
    const int m0 = by * 128, n0 = bx * 96;

    const f16_t* Asrc1 = A1 + hoff + aoff;
    const f16_t* Bsrc1 = B1 + hoff + boff;
    const f16_t* Bsrc2 = dual ? B2 + hoff + boff : nullptr;
    const f16_t* Pq1 = P1 ? P1 + hoff + poff : nullptr;
    const f16_t* Pq2 = P2 ? P2 + hoff + poff : nullptr;
    f16_t* Dq1 = D1 + hoff + doff;
    f16_t* Dq2 = D2 ? D2 + hoff + doff : nullptr;

    const int lane = tid & 63, w4 = tid >> 6;
    const int wm = (w4 & 1) * 64, wn = (w4 >> 1) * 48;
    const int lm = lane & 15, quad = lane >> 4;
    const int psw = (quad ^ ((lm >> 1) & 3)) * 8;

    // A staging: 512 16B-slots (128 rows x 4 chunks), 2 calls
    const f16_t* gApt[2]; int aslot[2];
#pragma unroll
    for (int cc = 0; cc < 2; ++cc) {
        int s = cc * 256 + w4 * 64 + lane;   // 0..511
        int row = s >> 2, pos = s & 3;
        int chunk = pos ^ ((row >> 1) & 3);
        gApt[cc] = Asrc1 + (size_t)(m0 + row) * K + chunk * 8;
        aslot[cc] = s * 8;
    }
    // B staging: dual = 768 slots (2 lev x 96 rows x 4 chunks), 3 calls;
    // single = 384 slots (lev 0 only): cc=0 full, cc=1 first 2 waves, cc=2 off
    const f16_t* gBpt[3]; int bslot[3]; bool bact[3];
#pragma unroll
    for (int cc = 0; cc < 3; ++cc) {
        int slot = cc * 256 + w4 * 64 + lane;
        bact[cc] = dual || (slot < 384);
        int lev = slot >= 384 ? 1 : 0;
        int s = slot - lev * 384;
        int row = s >> 2, pos = s & 3;
        int chunk = pos ^ ((row >> 1) & 3);
        const f16_t* bs = (lev && dual) ? Bsrc2 : Bsrc1;
        gBpt[cc] = bs + (size_t)(n0 + row) * K + chunk * 8;
        bslot[cc] = lev * 3072 + s * 8;
    }

    f32x4 acc[4][3] = {};

    // preload K-chunk 0 into buffer 0
#pragma unroll
    for (int cc = 0; cc < 2; ++cc) gl_lds16(gApt[cc], &sA[0][aslot[cc]]);
#pragma unroll
    for (int cc = 0; cc < 3; ++cc)
        if (bact[cc]) gl_lds16(gBpt[cc], &sB[0][bslot[cc]]);
    __syncthreads();

    int ib = 0;
    for (int kb = 0; kb < K; kb += 32, ib ^= 1) {
        // prefetch next chunk into the other buffer (overlaps MFMA below)
        if (kb + 32 < K) {
            int nb = ib ^ 1;
#pragma unroll
            for (int cc = 0; cc < 2; ++cc)
                gl_lds16(gApt[cc] + kb + 32, &sA[nb][aslot[cc]]);
#pragma unroll
            for (int cc = 0; cc < 3; ++cc)
                if (bact[cc]) gl_lds16(gBpt[cc] + kb + 32, &sB[nb][bslot[cc]]);
        }

        f16x8 bfr[2][3];
#pragma unroll
        for (int fn = 0; fn < 3; ++fn)
            bfr[0][fn] = *(const f16x8*)&sB[ib][(wn + fn * 16 + lm) * 32 + psw];
        if (dual) {
#pragma unroll
            for (int fn = 0; fn < 3; ++fn)
                bfr[1][fn] = *(const f16x8*)&sB[ib][3072 +
                                                (wn + fn * 16 + lm) * 32 + psw];
        }
#pragma unroll
        for (int fm = 0; fm < 4; ++fm) {
            f16x8 a1v = *(const f16x8*)&sA[ib][(wm + fm * 16 + lm) * 32 + psw];
#pragma unroll
            for (int fn = 0; fn < 3; ++fn) {
                acc[fm][fn] = __builtin_amdgcn_mfma_f32_16x16x32_f16(
                    a1v, bfr[0][fn], acc[fm][fn], 0, 0, 0);
                if (dual)
                    acc[fm][fn] = __builtin_amdgcn_mfma_f32_16x16x32_f16(
                        a1v, bfr[1][fn], acc[fm][fn], 0, 0, 0);
            }
        }
        // barrier: (a) all waves done reading buf ib (safe to overwrite at
        // kb+64), (b) vmcnt(0) drain -> buf ib^1 staged (loads overlapped
        // the MFMA section above)
        __syncthreads();
    }

    // epilogue: C/D layout col=lane&15, row=quad*4+reg  [verified m89/m91]
#pragma unroll
    for (int fm = 0; fm < 4; ++fm)
#pragma unroll
        for (int fn = 0; fn < 3; ++fn) {
            int col = n0 + wn + fn * 16 + lm;
#pragma unroll
            for (int r = 0; r < 4; ++r) {
                int row = m0 + wm + fm * 16 + quad * 4 + r;
                float val = acc[fm][fn][r];
                if (mode == 3) {
                    Dq1[(size_t)row * ldc + coloff + col] = (f16_t)val;
                } else if (mode == 1) {
                    Dq1[(size_t)row * ldc + col] = (f16_t)val;
                    if (D3) D3[(size_t)row * 3840 + col] = (f16_t)val;
                } else {
                    size_t o = (size_t)row * ldc + col;
                    val = 2.0f * val - ((float)Pq1[o] + (float)Pq2[o]);
                    f16_t h1, h2;
                    split2h(val, h1, h2);
                    Dq1[o] = h1; Dq2[o] = h2;
                }
            }
        }
}

// ---------------------------------------------------------------------------
// Gate kernel (all f16). R28: TWO blocks per row m (grid 1536, 3 tiles
// each), 24.5 KB LDS (sC dbuf 13K + sB 10K + red 1K). launch_bounds
// (256,3): cap 170 — the allocator setting this kernel has always
// compiled spill-free under (~84 regs) -> 4 waves/SIMD, 4 blocks/CU,
// 16 waves/CU (+33% over grid-768's 12). Fragment-layout h/c (all
// accesses full-64B-line):
//   addr(p,o) = (p>>4)*512 + (o>>2)*64 + (p&15)*4 + (o&3)
// 2-barrier/tile schedule.
// ---------------------------------------------------------------------------
__global__ __launch_bounds__(256, 3) void gate_theta_mfma(
    const f16_t* __restrict__ Cbf, const f16_t* __restrict__ thstack,
    const f16_t* __restrict__ Wstack,
    const float* __restrict__ bfv, const float* __restrict__ biv,
    const float* __restrict__ bov, const float* __restrict__ bcv,
    const float* __restrict__ Wout, const float* __restrict__ bout,
    f16_t* __restrict__ h, f16_t* __restrict__ c, float* __restrict__ x,
    int first, int last)
{
    __shared__ __align__(16) ushort_t sC[2][26 * 128];  // 13 KB dbuf
    __shared__ __align__(16) ushort_t sB[128 * 40];     // 10 KB
    __shared__ float red[256];                          // 1 KB

    const int tid = threadIdx.x;
    const int lane = tid & 63, w4 = tid >> 6;
    const int wm = (w4 & 1) * 64, wn = (w4 >> 1) * 64;
    const int lm = lane & 15, quad = lane >> 4;
    const int m = blockIdx.x >> 1;
    const int colbase = (blockIdx.x & 1) * 384;
    const int o0 = (wm >> 2) + quad * 4;
    const int pw = w4 * 32;
    const size_t ogOff = (size_t)(o0 >> 2) * 64;   // fragment o-group offset

    // ones rows (bias-via-MFMA) once into both buffers
    if (tid < 32) {
        uint4 ones;
        ones.x = ones.y = ones.z = ones.w = 0x3C003C00u;  // f16 1.0 x2
        *(uint4*)&sC[tid >> 4][25 * 128 + (tid & 15) * 8] = ones;
    }

    // stage tile t (local 0..2) -> sC[buf] rows 0..24 (async, 400 x 16B)
    auto stage = [&](int t, int buf) {
        int n0 = colbase + t * 128;
#pragma unroll
        for (int cc = 0; cc < 2; ++cc) {
            int s = cc * 256 + tid;
            if (s < 400) {
                int ij = s >> 4, f = s & 15;
                int i5 = (ij * 205) >> 10;       // ij/5 for ij<32
                int j5 = ij - i5 * 5;
                size_t ga = (size_t)(i5 * DIM + m) * 3840 + j5 * DIM + n0 + f * 8;
                gl_lds16(&Cbf[ga], (f16_t*)&sC[buf][ij * 128 + f * 8]);
            }
        }
    };

    // uniform operands, once per block
    f16x8 bth[2];
#pragma unroll
    for (int fn = 0; fn < 2; ++fn)
        bth[fn] = *(const f16x8*)&thstack[(fn * 16 + lm) * 32 + quad * 8];
    f16x8 af[4][2];
#pragma unroll
    for (int fm = 0; fm < 4; ++fm)
#pragma unroll
        for (int kc = 0; kc < 2; ++kc)
            af[fm][kc] = *(const f16x8*)&Wstack[(wm + fm * 16 + lm) * 64 +
                                                kc * 32 + quad * 8];
    const float4 bgf = *(const float4*)&bfv[o0];
    const float4 bgi = *(const float4*)&biv[o0];
    const float4 bgo = *(const float4*)&bov[o0];
    const float4 bgc = *(const float4*)&bcv[o0];
    const float4 wo4 = *(const float4*)&Wout[o0];
    float bf4[4] = {bgf.x, bgf.y, bgf.z, bgf.w};
    float bi4[4] = {bgi.x, bgi.y, bgi.z, bgi.w};
    float bo4[4] = {bgo.x, bgo.y, bgo.z, bgo.w};
    float bc4[4] = {bgc.x, bgc.y, bgc.z, bgc.w};
    float wo[4] = {wo4.x, wo4.y, wo4.z, wo4.w};
    const float bout0 = bout[0];

    // prologue: stage tiles 0 and 1
    stage(0, 0);
    stage(1, 1);
    __syncthreads();   // ones + tiles 0,1 staged

    for (int t = 0; t < 3; ++t) {
        const int tb = t & 1;
        const int pbase = m * DIM + colbase + t * 128;

        // ---- theta: xc = Cbf-tile^T x theta (+bias via ones row) -> sB ----
        {
            const f16_t* sCf = (const f16_t*)sC[tb];
            f32x4 tacc[2][2] = {};
            f16x8 a0, a1;
#pragma unroll
            for (int j = 0; j < 8; ++j) {
                int k = quad * 8 + j;
                int ij = k > 25 ? 25 : k;   // k>25 hits ones row x thstack 0
                a0[j] = sCf[ij * 128 + pw + lm];
                a1[j] = sCf[ij * 128 + pw + 16 + lm];
            }
#pragma unroll
            for (int fn = 0; fn < 2; ++fn) {
                tacc[0][fn] = __builtin_amdgcn_mfma_f32_16x16x32_f16(
                    a0, bth[fn], tacc[0][fn], 0, 0, 0);
                tacc[1][fn] = __builtin_amdgcn_mfma_f32_16x16x32_f16(
                    a1, bth[fn], tacc[1][fn], 0, 0, 0);
            }
#pragma unroll
            for (int fm2 = 0; fm2 < 2; ++fm2)
#pragma unroll
                for (int fn = 0; fn < 2; ++fn)
#pragma unroll
                    for (int r = 0; r < 4; ++r) {
                        f16_t hv = (f16_t)tacc[fm2][fn][r];
                        sB[(pw + fm2 * 16 + quad * 4 + r) * 40 +
                           fn * 16 + lm] = __builtin_bit_cast(ushort_t, hv);
                    }
        }
        __syncthreads();   // sB visible (also drains any staging leftovers)

        // ---- gate phase ----
        // stage tile 2 into sC[0] during gate(0): read by theta(2), with
        // two barriers in between (drained at the end-of-gate barrier)
        if (t == 0) stage(2, 0);

        // h/c for this tile: fragment layout, full-line wave-contiguous
        f16x8 hfr[4];
        f16_t cold[4][4];
        if (!first) {
#pragma unroll
            for (int fn = 0; fn < 4; ++fn) {
                size_t p = (size_t)(pbase + wn + fn * 16 + lm);
                size_t fb = (p >> 4) * 512 + (size_t)(p & 15) * 4;
                uint2 l0 = *(const uint2*)&h[fb + (size_t)(quad * 2) * 64];
                uint2 l1 = *(const uint2*)&h[fb + (size_t)(quad * 2 + 1) * 64];
                uint4 hv; hv.x = l0.x; hv.y = l0.y; hv.z = l1.x; hv.w = l1.y;
                hfr[fn] = __builtin_bit_cast(f16x8, hv);
                *(uint2*)cold[fn] = *(const uint2*)&c[fb + ogOff];
            }
        } else {
#pragma unroll
            for (int fn = 0; fn < 4; ++fn) {
#pragma unroll
                for (int j = 0; j < 8; ++j) hfr[fn][j] = (f16_t)0.0f;
#pragma unroll
                for (int r = 0; r < 4; ++r) cold[fn][r] = (f16_t)0.0f;
            }
        }

#pragma unroll
        for (int fn = 0; fn < 4; ++fn) {
            f16x8 bxc = *(const f16x8*)&sB[(wn + fn * 16 + lm) * 40 +
                                           quad * 8];
            f32x4 acc[4] = {};
#pragma unroll
            for (int fm = 0; fm < 4; ++fm) {
                acc[fm] = __builtin_amdgcn_mfma_f32_16x16x32_f16(
                    af[fm][0], bxc, acc[fm], 0, 0, 0);
                acc[fm] = __builtin_amdgcn_mfma_f32_16x16x32_f16(
                    af[fm][1], hfr[fn], acc[fm], 0, 0, 0);
            }

            int px = wn + fn * 16 + lm;
            size_t p = (size_t)(pbase + px);
            size_t fb = (p >> 4) * 512 + (size_t)(p & 15) * 4;
            f16_t cn16[4], hn16[4];
            float part = 0.f;
#pragma unroll
            for (int r = 0; r < 4; ++r) {
                float fg = sigm(acc[0][r] + bf4[r]);
                float ig = sigm(acc[1][r] + bi4[r]);
                float og = sigm(acc[2][r] + bo4[r]);
                float gg = sigm(acc[3][r] + bc4[r]);
                float cn = fg * (float)cold[fn][r] + ig * gg;
                cn16[r] = (f16_t)cn;
                hn16[r] = (f16_t)(og * sigm(cn));
                part = fmaf(cn, wo[r], part);
            }
            if (!last) {
                *(uint2*)&c[fb + ogOff] = *(const uint2*)cn16;
                *(uint2*)&h[fb + ogOff] = *(const uint2*)hn16;
            }
            part += __shfl_xor(part, 16, 64);
            part += __shfl_xor(part, 32, 64);
            if (quad == 0) red[px * 2 + (wm >> 6)] = part;
        }
        __syncthreads();   // red visible; tile-2 staging drained

        // ---- x-tail (red has no writer until after the next barrier) ----
        if (tid < 128) {
            float v = red[tid * 2] + red[tid * 2 + 1] + bout0;
            v = fminf(fmaxf(v, -15.f), 15.f);
            float e = __expf(2.f * v);
            x[pbase + tid] += (e - 1.f) * __builtin_amdgcn_rcpf(e + 1.f);
        }
    }
}

// ---------------------------------------------------------------------------
extern "C" void kernel_launch(void* const* d_in, const int* in_sizes, int n_in,
                              void* d_out, int out_size, void* d_ws, size_t ws_size,
                              hipStream_t stream)
{
    const float* x_in  = (const float*)d_in[0];
    const float* Lrow  = (const float*)d_in[1];
    const float* Lcol  = (const float*)d_in[2];
    const float* theta = (const float*)d_in[3];
    const float* bias  = (const float*)d_in[4];
    const float* Wf = (const float*)d_in[5];
    const float* Uf = (const float*)d_in[6];
    const float* bf = (const float*)d_in[7];
    const float* Wi = (const float*)d_in[8];
    const float* Ui = (const float*)d_in[9];
    const float* bi = (const float*)d_in[10];
    const float* Wo = (const float*)d_in[11];
    const float* Uo = (const float*)d_in[12];
    const float* bo = (const float*)d_in[13];
    const float* Wc = (const float*)d_in[14];
    const float* Uc = (const float*)d_in[15];
    const float* bc = (const float*)d_in[16];
    const float* Wout = (const float*)d_in[17];
    const float* bout = (const float*)d_in[18];
    (void)in_sizes; (void)n_in; (void)out_size;

    float* out = (float*)d_out;   // working x buffer

    // ---- workspace pool (136.9 MB) ----
    f16_t* base = (f16_t*)d_ws;
    f16_t* Cbf  = base;                              // 14,745,600 f16
    f16_t* h    = Cbf + 14745600;                    // 18,874,368 f16
    f16_t* c    = h + 18874368;                      // 18,874,368 f16
    f16_t* S0   = c + 18874368;                      // 2*STK (Tr | Tc)
    f16_t* S1   = S0 + 2 * STK;
    f16_t* XR0  = S1 + 2 * STK;                      // STK (single level)
    f16_t* Wstack  = XR0 + STK;                      // 8192
    f16_t* thstack = Wstack + 8192;                  // 1024
    f16_t* xT0  = thstack + 1024;                    // MXK
    f16_t* xT1  = xT0 + MXK;                         // MXK
    if (ws_size < (size_t)136857600) return;

    hipMemcpyAsync(out, x_in, (size_t)MXK * 4, hipMemcpyDeviceToDevice, stream);

    prep_gate<<<36, 256, 0, stream>>>(Wf, Wi, Wo, Wc, Uf, Ui, Uo, Uc, theta,
                                      bias, Wstack, thstack);
    init_split<<<MXK / 256, 256, 0, stream>>>(Lrow, Lcol, S0, S1);
    // T2 = 2*L@L - T0 (Tr+Tc dual stack): A = L hi, B = L dual
    gemm_bt_h2<<<96, 256, 0, stream>>>(
        S0 + MXK, S0 + MXK, S1 + MXK, S0, S1,
        S0 + 2 * MXK, S1 + 2 * MXK, nullptr,
        DIM, DIM, 2, 8, STK, 0);
    // T3 = 2*L@T2 - T1  AND  T4 = 2*T2@T2 - T0, both stacks, one launch
    gemm_bt_h2<<<192, 256, 0, stream>>>(
        S0, S0, S1, S0, S1, S0, S1, nullptr,
        DIM, DIM, 4, 8, STK, 0);

    for (int it = 0; it < 3; ++it) {
        // xT dual split + x f16 into XR rows 0..767 + Cbf rows 0..767 (j0)
        transpose_cvt2x<<<dim3(24, 24), 256, 0, stream>>>(out, xT0, xT1,
                                                          XR0, Cbf);
        // stage1: XR rows 768..3839 = T_{1..4} @ x (f16 single out, dual B);
        // also Cbf j0 rows 768+
        gemm_bt_h2<<<192, 256, 0, stream>>>(
            S0 + MXK, xT0, xT1,
            nullptr, nullptr,
            XR0 + MXK, nullptr, Cbf + (size_t)DIM * 3840,
            DIM, DIM, 1, 8, 0, 0);
        // stage2: Cbf cols 768.. = XR @ Tc_{1..4}^T (M=3840, N=3072, K=768)
        // single-product (B2 = nullptr): A is f16-rounded and D stored f16,
        // so the B residual term is below existing rounding error
        gemm_bt_h2<<<960, 256, 0, stream>>>(
            XR0, S0 + STK + MXK, nullptr,
            nullptr, nullptr,
            Cbf, nullptr, nullptr, DIM, 3840, 3, 32, 0, DIM);
        // gates: theta-MFMA + gate-MFMA + LSTM + x += tanh(c.Wout+b)
        gate_theta_mfma<<<1536, 256, 0, stream>>>(
            Cbf, thstack, Wstack,
            bf, bi, bo, bc, Wout, bout, h, c, out,
            it == 0 ? 1 : 0, it == 2 ? 1 : 0);
    }
}

// Round 14
// 420.539 us; speedup vs baseline: 1.6680x; 1.0252x over previous
//
#include <hip/hip_runtime.h>
#include <hip/hip_bf16.h>
#include <stdint.h>

// ---------------------------------------------------------------------------
// MGCNN on MI355X — 2-product f16 MFMA conv + all-f16 MFMA gate kernel.
//
// Number format: B operands dual-level (b = b1 + b2), b1 = (f16)v,
// b2 = (f16)(v - b1) stored UNSCALED. Both products accumulate into ONE
// f32 accumulator:  acc = mfma(a, b1, acc); acc = mfma(a, b2, acc)
//
// R29: gate reverted to the R25 plateau config (grid 768, 12 waves/CU,
// 45.8 us — R28's clean 16-wave test REGRESSED to 53.4 us: second
// scheduling round + halved pipeline depth beat added concurrency; 7
// structural attacks all falsified -> declared plateau). New change:
// stage1 single-product, same argument as R20's stage2 win: stage1's A
// is T_hi only (S1 residuals never read there) and XR is stored f16, so
// the dual-B term is one of three comparable 2^-11 error terms; dropping
// it scales error by <=sqrt(2). Halves stage1 MFMAs (192 blocks x 3).
// GEMMs keep R25's XCD swizzle. Risk: absmax may rise 0.03125 -> ~0.05.
// ---------------------------------------------------------------------------

#define DIM 768
#define MXK 589824        // 768*768
#define STK 2949120       // 5*768*768

typedef _Float16 f16x8 __attribute__((ext_vector_type(8)));
typedef float f32x4 __attribute__((ext_vector_type(4)));
typedef unsigned short ushort_t;
typedef _Float16 f16_t;

__device__ __forceinline__ float sigm(float v) {
    float e = __expf(-v);
    return __builtin_amdgcn_rcpf(1.0f + e);   // raw v_rcp_f32, ~1 ulp
}
__device__ __forceinline__ void split2h(float f, f16_t& h1, f16_t& h2) {
    h1 = (f16_t)f;
    h2 = (f16_t)(f - (float)h1);   // unscaled residual (shared-acc scheme)
}

// async 16B global->LDS (LDS dest = wave-uniform base + lane*16)
__device__ __forceinline__ void gl_lds16(const f16_t* g, f16_t* l) {
    auto gp = reinterpret_cast<const __attribute__((address_space(1))) uint32_t*>(
        reinterpret_cast<uintptr_t>(g));
    auto lp = reinterpret_cast<__attribute__((address_space(3))) uint32_t*>(
        reinterpret_cast<uintptr_t>(l));
    __builtin_amdgcn_global_load_lds(gp, lp, 16, 0, 0);
}

// ---------------------------------------------------------------------------
// init: T0 = I, T1 = L  ->  f16x2s, Tr stack then Tc stack per level
// ---------------------------------------------------------------------------
__global__ __launch_bounds__(256) void init_split(
    const float* __restrict__ Lrow, const float* __restrict__ Lcol,
    f16_t* __restrict__ S0, f16_t* __restrict__ S1)
{
    int idx = blockIdx.x * 256 + threadIdx.x;
    int p = idx / DIM, m = idx % DIM;
    f16_t eye = (p == m) ? (f16_t)1.0f : (f16_t)0.0f;
    S0[idx] = eye; S1[idx] = (f16_t)0.0f;
    S0[STK + idx] = eye; S1[STK + idx] = (f16_t)0.0f;
    f16_t h1, h2;
    split2h(Lrow[idx], h1, h2);
    S0[MXK + idx] = h1; S1[MXK + idx] = h2;
    split2h(Lcol[idx], h1, h2);
    S0[STK + MXK + idx] = h1; S1[STK + MXK + idx] = h2;
}

// ---------------------------------------------------------------------------
// prep: Wstack f16 [128 R][64 k] and thstack f16 [32 o][32 k=ij]
// (k=25 -> bias row, pairs with the ones-row staged into sC; k>25 -> 0)
// ---------------------------------------------------------------------------
__global__ __launch_bounds__(256) void prep_gate(
    const float* __restrict__ Wf, const float* __restrict__ Wi,
    const float* __restrict__ Wo, const float* __restrict__ Wc,
    const float* __restrict__ Uf, const float* __restrict__ Ui,
    const float* __restrict__ Uo, const float* __restrict__ Uc,
    const float* __restrict__ theta, const float* __restrict__ biasv,
    f16_t* __restrict__ Wstack, f16_t* __restrict__ thstack)
{
    int idx = blockIdx.x * 256 + threadIdx.x;
    if (idx < 8192) {
        int R = idx >> 6, k = idx & 63;
        int g = (R >> 4) & 3, o = (R >> 6) * 16 + (R & 15);
        const float* Wg[4] = {Wf, Wi, Wo, Wc};
        const float* Ug[4] = {Uf, Ui, Uo, Uc};
        float v = (k < 32) ? Wg[g][k * 32 + o] : Ug[g][(k - 32) * 32 + o];
        Wstack[idx] = (f16_t)v;
    } else if (idx < 9216) {
        int t = idx - 8192;
        int o = t >> 5, k = t & 31;
        float v = (k < 25) ? theta[k * 32 + o]
                           : (k == 25 ? biasv[o] : 0.0f);
        thstack[o * 32 + k] = (f16_t)v;
    }
}

// ---------------------------------------------------------------------------
// transpose 768x768 + f16x2s split: xT[q][p] = x[p][q] (dual, B of stage1);
// straight f16 single into XR rows 0..767 (A of stage2, T_0 = I) and into
// Cbf rows 0..767 cols 0..767 (T_0 = I both sides).
// ---------------------------------------------------------------------------
__global__ __launch_bounds__(256) void transpose_cvt2x(
    const float* __restrict__ in, f16_t* __restrict__ o1,
    f16_t* __restrict__ o2, f16_t* __restrict__ xr0,
    f16_t* __restrict__ Cbf)
{
    __shared__ float t[32][33];
    int x = threadIdx.x & 31, y = threadIdx.x >> 5;
    int bx = blockIdx.x * 32, by = blockIdx.y * 32;
#pragma unroll
    for (int r = 0; r < 4; ++r) {
        int p = by + y + 8 * r, q = bx + x;
        size_t oi = (size_t)p * DIM + q;
        float v = in[oi];
        t[y + 8 * r][x] = v;
        f16_t hv = (f16_t)v;
        xr0[oi] = hv;
        Cbf[(size_t)p * 3840 + q] = hv;
    }
    __syncthreads();
#pragma unroll
    for (int r = 0; r < 4; ++r) {
        float v = t[x][y + 8 * r];
        f16_t h1, h2;
        split2h(v, h1, h2);
        size_t o = (size_t)(bx + y + 8 * r) * DIM + by + x;
        o1[o] = h1; o2[o] = h2;
    }
}

// ---------------------------------------------------------------------------
// 2-product f16 MFMA GEMM engine, double-buffered LDS (B-transposed,
// k-contig), 128x96 block, BK=32, 4 waves, wave tile 64x48.
// Shared accumulator (R18): acc[4][3] -> __launch_bounds__(256,4),
// 4 blocks/CU (LDS 160 KiB exactly), single scheduling round at 960 blocks.
// R20: B2 == nullptr -> single-product. R25: XCD-aware bijective block
// swizzle (all launches have nwg%8==0) -> contiguous logical chunk per
// XCD -> A/B panel reuse lands in the private 4MB L2.
// mode 1: f16 single out D1 (ldc) + optional D3 (ld 3840);
// mode 2: cheb T2 (v = 2*acc - P), dual out, dual stack via halfStride;
// mode 3: f16 single out (+coloff), supertile (nbx=32);
// mode 4: batched cheb T3+T4 (offset table; pass S0/S1 bases).
// ---------------------------------------------------------------------------
__global__ __launch_bounds__(256, 4) void gemm_bt_h2(
    const f16_t* __restrict__ A1,
    const f16_t* __restrict__ B1, const f16_t* __restrict__ B2,
    const f16_t* __restrict__ P1, const f16_t* __restrict__ P2,
    f16_t* __restrict__ D1, f16_t* __restrict__ D2, f16_t* __restrict__ D3,
    int K, int ldc, int mode, int nbx, int halfStride, int coloff)
{
    __shared__ __align__(16) f16_t sA[2][128 * 32];       // 2 x 8 KB
    __shared__ __align__(16) f16_t sB[2][2 * 96 * 32];    // 2 x 12 KB

    const int tid = threadIdx.x;
    const bool dual = (B2 != nullptr);

    // XCD-aware bijective swizzle (T1): blocks on one XCD (= blockIdx%8)
    // get a CONTIGUOUS chunk of logical ids, so panel reuse stays in that
    // XCD's private L2 instead of striping across all 8 XCDs.
    int g = blockIdx.x;
    {
        int nwg = gridDim.x;
        if ((nwg & 7) == 0) g = (g & 7) * (nwg >> 3) + (g >> 3);
    }

    int bx, by;
    size_t hoff = 0;
    int aoff = 0, boff = 0, poff = 0, doff = 0;
    if (mode == 3) {
        // supertile: 8 rows x 32 cols share A/B panels -> L2 reuse
        int sup = g >> 8;                   // / (8*32)
        int rows0 = sup * 8;
        int H = 30 - rows0; if (H > 8) H = 8;
        int local = g - rows0 * nbx;
        by = rows0 + local % H;
        bx = local / H;
    } else if (mode == 4) {
        // T3 = 2*L@T2 - T1 (g<96), T4 = 2*T2@T2 - T0 (g>=96); Tr|Tc stacks
        int t34 = g / 96, r = g % 96;
        int stack = r / 48, rr = r % 48;
        by = rr >> 3; bx = rr & 7;
        hoff = (size_t)stack * halfStride;
        if (t34 == 0) { aoff = MXK; boff = 2 * MXK; poff = MXK; doff = 3 * MXK; }
        else          { aoff = 2 * MXK; boff = 2 * MXK; poff = 0; doff = 4 * MXK; }
    } else {
        bx = g % nbx;
        by = g / nbx;
        if (mode == 2 && by >= 6) { by -= 6; hoff = (size_t)halfStride; }
    }
    const int m0 = by * 128, n0 = bx * 96;

    const f16_t* Asrc1 = A1 + hoff + aoff;
    const f16_t* Bsrc1 = B1 + hoff + boff;
    const f16_t* Bsrc2 = dual ? B2 + hoff + boff : nullptr;
    const f16_t* Pq1 = P1 ? P1 + hoff + poff : nullptr;
    const f16_t* Pq2 = P2 ? P2 + hoff + poff : nullptr;
    f16_t* Dq1 = D1 + hoff + doff;
    f16_t* Dq2 = D2 ? D2 + hoff + doff : nullptr;

    const int lane = tid & 63, w4 = tid >> 6;
    const int wm = (w4 & 1) * 64, wn = (w4 >> 1) * 48;
    const int lm = lane & 15, quad = lane >> 4;
    const int psw = (quad ^ ((lm >> 1) & 3)) * 8;

    // A staging: 512 16B-slots (128 rows x 4 chunks), 2 calls
    const f16_t* gApt[2]; int aslot[2];
#pragma unroll
    for (int cc = 0; cc < 2; ++cc) {
        int s = cc * 256 + w4 * 64 + lane;   // 0..511
        int row = s >> 2, pos = s & 3;
        int chunk = pos ^ ((row >> 1) & 3);
        gApt[cc] = Asrc1 + (size_t)(m0 + row) * K + chunk * 8;
        aslot[cc] = s * 8;
    }
    // B staging: dual = 768 slots (2 lev x 96 rows x 4 chunks), 3 calls;
    // single = 384 slots (lev 0 only): cc=0 full, cc=1 first 2 waves, cc=2 off
    const f16_t* gBpt[3]; int bslot[3]; bool bact[3];
#pragma unroll
    for (int cc = 0; cc < 3; ++cc) {
        int slot = cc * 256 + w4 * 64 + lane;
        bact[cc] = dual || (slot < 384);
        int lev = slot >= 384 ? 1 : 0;
        int s = slot - lev * 384;
        int row = s >> 2, pos = s & 3;
        int chunk = pos ^ ((row >> 1) & 3);
        const f16_t* bs = (lev && dual) ? Bsrc2 : Bsrc1;
        gBpt[cc] = bs + (size_t)(n0 + row) * K + chunk * 8;
        bslot[cc] = lev * 3072 + s * 8;
    }

    f32x4 acc[4][3] = {};

    // preload K-chunk 0 into buffer 0
#pragma unroll
    for (int cc = 0; cc < 2; ++cc) gl_lds16(gApt[cc], &sA[0][aslot[cc]]);
#pragma unroll
    for (int cc = 0; cc < 3; ++cc)
        if (bact[cc]) gl_lds16(gBpt[cc], &sB[0][bslot[cc]]);
    __syncthreads();

    int ib = 0;
    for (int kb = 0; kb < K; kb += 32, ib ^= 1) {
        // prefetch next chunk into the other buffer (overlaps MFMA below)
        if (kb + 32 < K) {
            int nb = ib ^ 1;
#pragma unroll
            for (int cc = 0; cc < 2; ++cc)
                gl_lds16(gApt[cc] + kb + 32, &sA[nb][aslot[cc]]);
#pragma unroll
            for (int cc = 0; cc < 3; ++cc)
                if (bact[cc]) gl_lds16(gBpt[cc] + kb + 32, &sB[nb][bslot[cc]]);
        }

        f16x8 bfr[2][3];
#pragma unroll
        for (int fn = 0; fn < 3; ++fn)
            bfr[0][fn] = *(const f16x8*)&sB[ib][(wn + fn * 16 + lm) * 32 + psw];
        if (dual) {
#pragma unroll
            for (int fn = 0; fn < 3; ++fn)
                bfr[1][fn] = *(const f16x8*)&sB[ib][3072 +
                                                (wn + fn * 16 + lm) * 32 + psw];
        }
#pragma unroll
        for (int fm = 0; fm < 4; ++fm) {
            f16x8 a1v = *(const f16x8*)&sA[ib][(wm + fm * 16 + lm) * 32 + psw];
#pragma unroll
            for (int fn = 0; fn < 3; ++fn) {
                acc[fm][fn] = __builtin_amdgcn_mfma_f32_16x16x32_f16(
                    a1v, bfr[0][fn], acc[fm][fn], 0, 0, 0);
                if (dual)
                    acc[fm][fn] = __builtin_amdgcn_mfma_f32_16x16x32_f16(
                        a1v, bfr[1][fn], acc[fm][fn], 0, 0, 0);
            }
        }
        // barrier: (a) all waves done reading buf ib (safe to overwrite at
        // kb+64), (b) vmcnt(0) drain -> buf ib^1 staged (loads overlapped
        // the MFMA section above)
        __syncthreads();
    }

    // epilogue: C/D layout col=lane&15, row=quad*4+reg  [verified m89/m91]
#pragma unroll
    for (int fm = 0; fm < 4; ++fm)
#pragma unroll
        for (int fn = 0; fn < 3; ++fn) {
            int col = n0 + wn + fn * 16 + lm;
#pragma unroll
            for (int r = 0; r < 4; ++r) {
                int row = m0 + wm + fm * 16 + quad * 4 + r;
                float val = acc[fm][fn][r];
                if (mode == 3) {
                    Dq1[(size_t)row * ldc + coloff + col] = (f16_t)val;
                } else if (mode == 1) {
                    Dq1[(size_t)row * ldc + col] = (f16_t)val;
                    if (D3) D3[(size_t)row * 3840 + col] = (f16_t)val;
                } else {
                    size_t o = (size_t)row * ldc + col;
                    val = 2.0f * val - ((float)Pq1[o] + (float)Pq2[o]);
                    f16_t h1, h2;
                    split2h(val, h1, h2);
                    Dq1[o] = h1; Dq2[o] = h2;
                }
            }
        }
}

// ---------------------------------------------------------------------------
// Gate kernel (all f16). R25 plateau config (declared best: 45.8 us/disp,
// 7 structural variants falsified). Grid 768, single-barrier pipeline.
// Per phase t:
//   tail(t-1) | stage(t+2)->sC[t&1] | theta(t+1): sC[(t+1)&1]->sB[(t+1)&1]
//   | h/c prefetch(t+1) | gate(t): sB[t&1]+hfr -> h/c stores, red[t&1]
//   | barrier
// ---------------------------------------------------------------------------
__global__ __launch_bounds__(256, 3) void gate_theta_mfma(
    const f16_t* __restrict__ Cbf, const f16_t* __restrict__ thstack,
    const f16_t* __restrict__ Wstack,
    const float* __restrict__ bfv, const float* __restrict__ biv,
    const float* __restrict__ bov, const float* __restrict__ bcv,
    const float* __restrict__ Wout, const float* __restrict__ bout,
    f16_t* __restrict__ h, f16_t* __restrict__ c, float* __restrict__ x,
    int first, int last)
{
    __shared__ __align__(16) ushort_t sC[2][26 * 128];  // 2 x 6.5 KB
    __shared__ __align__(16) ushort_t sB[2][128 * 40];  // 2 x 10 KB
    __shared__ float red[2][256];                       // 2 KB

    const int tid = threadIdx.x;
    const int lane = tid & 63, w4 = tid >> 6;
    const int wm = (w4 & 1) * 64, wn = (w4 >> 1) * 64;
    const int lm = lane & 15, quad = lane >> 4;
    const int m = blockIdx.x;
    const int o0 = (wm >> 2) + quad * 4;
    const int pw = w4 * 32;

    // ones rows (bias-via-MFMA) once into both buffers
    if (tid < 32) {
        uint4 ones;
        ones.x = ones.y = ones.z = ones.w = 0x3C003C00u;  // f16 1.0 x2
        *(uint4*)&sC[tid >> 4][25 * 128 + (tid & 15) * 8] = ones;
    }

    // stage tile with first col n0 -> sC[buf] rows 0..24 (async, 400 x 16B)
    auto stage = [&](int n0, int buf) {
#pragma unroll
        for (int cc = 0; cc < 2; ++cc) {
            int s = cc * 256 + tid;
            if (s < 400) {
                int ij = s >> 4, f = s & 15;
                int i5 = (ij * 205) >> 10;       // ij/5 for ij<32
                int j5 = ij - i5 * 5;
                size_t ga = (size_t)(i5 * DIM + m) * 3840 + j5 * DIM + n0 + f * 8;
                gl_lds16(&Cbf[ga], (f16_t*)&sC[buf][ij * 128 + f * 8]);
            }
        }
    };

    // uniform operands, once per block
    f16x8 bth[2];
#pragma unroll
    for (int fn = 0; fn < 2; ++fn)
        bth[fn] = *(const f16x8*)&thstack[(fn * 16 + lm) * 32 + quad * 8];
    f16x8 af[4][2];
#pragma unroll
    for (int fm = 0; fm < 4; ++fm)
#pragma unroll
        for (int kc = 0; kc < 2; ++kc)
            af[fm][kc] = *(const f16x8*)&Wstack[(wm + fm * 16 + lm) * 64 +
                                                kc * 32 + quad * 8];
    const float4 bgf = *(const float4*)&bfv[o0];
    const float4 bgi = *(const float4*)&biv[o0];
    const float4 bgo = *(const float4*)&bov[o0];
    const float4 bgc = *(const float4*)&bcv[o0];
    const float4 wo4 = *(const float4*)&Wout[o0];
    float bf4[4] = {bgf.x, bgf.y, bgf.z, bgf.w};
    float bi4[4] = {bgi.x, bgi.y, bgi.z, bgi.w};
    float bo4[4] = {bgo.x, bgo.y, bgo.z, bgo.w};
    float bc4[4] = {bgc.x, bgc.y, bgc.z, bgc.w};
    float wo[4] = {wo4.x, wo4.y, wo4.z, wo4.w};
    const float bout0 = bout[0];

    // theta phase: read sC[sbuf], write xc into sB[dbuf]
    auto theta = [&](int sbuf, int dbuf) {
        const f16_t* sCf = (const f16_t*)sC[sbuf];
        f32x4 tacc[2][2] = {};
        f16x8 a0, a1;
#pragma unroll
        for (int j = 0; j < 8; ++j) {
            int k = quad * 8 + j;
            int ij = k > 25 ? 25 : k;   // k>25 hits ones row x thstack 0
            a0[j] = sCf[ij * 128 + pw + lm];
            a1[j] = sCf[ij * 128 + pw + 16 + lm];
        }
#pragma unroll
        for (int fn = 0; fn < 2; ++fn) {
            tacc[0][fn] = __builtin_amdgcn_mfma_f32_16x16x32_f16(
                a0, bth[fn], tacc[0][fn], 0, 0, 0);
            tacc[1][fn] = __builtin_amdgcn_mfma_f32_16x16x32_f16(
                a1, bth[fn], tacc[1][fn], 0, 0, 0);
        }
#pragma unroll
        for (int fm2 = 0; fm2 < 2; ++fm2)
#pragma unroll
            for (int fn = 0; fn < 2; ++fn)
#pragma unroll
                for (int r = 0; r < 4; ++r) {
                    f16_t hv = (f16_t)tacc[fm2][fn][r];
                    sB[dbuf][(pw + fm2 * 16 + quad * 4 + r) * 40 +
                             fn * 16 + lm] = __builtin_bit_cast(ushort_t, hv);
                }
    };

    // x-tail for tile t (reads red[t&1]); call AFTER the barrier of phase t
    auto tail = [&](int t) {
        if (tid < 128) {
            float v = red[t & 1][tid * 2] + red[t & 1][tid * 2 + 1] + bout0;
            v = fminf(fmaxf(v, -15.f), 15.f);
            float e = __expf(2.f * v);
            x[m * DIM + t * 128 + tid] +=
                (e - 1.f) * __builtin_amdgcn_rcpf(e + 1.f);
        }
    };

    // prologue: stage tiles 0 and 1, load tile-0 h/c
    stage(0, 0);
    stage(128, 1);
    f16x8 hfr[4];
    f16_t cold[4][4];
    if (!first) {
#pragma unroll
        for (int fn = 0; fn < 4; ++fn) {
            size_t p = (size_t)(m * DIM + wn + fn * 16 + lm);
            hfr[fn] = *(const f16x8*)&h[p * 32 + quad * 8];
            *(uint2*)cold[fn] = *(const uint2*)&c[p * 32 + o0];
        }
    } else {
#pragma unroll
        for (int fn = 0; fn < 4; ++fn) {
#pragma unroll
            for (int j = 0; j < 8; ++j) hfr[fn][j] = (f16_t)0.0f;
#pragma unroll
            for (int r = 0; r < 4; ++r) cold[fn][r] = (f16_t)0.0f;
        }
    }
    __syncthreads();   // ones + tiles 0,1 staged
    theta(0, 0);
    __syncthreads();   // sB[0] visible

    for (int t = 0; t < 6; ++t) {
        const int tb = t & 1;
        const int pbase = m * DIM + t * 128;

        // tail of previous tile (red[(t-1)&1] made visible by last barrier)
        if (t > 0) tail(t - 1);

        // stage 2 tiles ahead into sC[tb] (read by theta(t+2) next phase)
        if (t + 2 < 6) stage((t + 2) * 128, tb);

        // theta for next tile into sB[tb^1]
        if (t + 1 < 6) theta(tb ^ 1, tb ^ 1);

        // h/c prefetch for next tile
        f16x8 hfr2[4];
        f16_t cold2[4][4];
        if (t + 1 < 6 && !first) {
#pragma unroll
            for (int fn = 0; fn < 4; ++fn) {
                size_t p = (size_t)(pbase + 128 + wn + fn * 16 + lm);
                hfr2[fn] = *(const f16x8*)&h[p * 32 + quad * 8];
                *(uint2*)cold2[fn] = *(const uint2*)&c[p * 32 + o0];
            }
        } else {
#pragma unroll
            for (int fn = 0; fn < 4; ++fn) {
#pragma unroll
                for (int j = 0; j < 8; ++j) hfr2[fn][j] = (f16_t)0.0f;
#pragma unroll
                for (int r = 0; r < 4; ++r) cold2[fn][r] = (f16_t)0.0f;
            }
        }

        // gate for tile t
#pragma unroll
        for (int fn = 0; fn < 4; ++fn) {
            f16x8 bxc = *(const f16x8*)&sB[tb][(wn + fn * 16 + lm) * 40 +
                                              quad * 8];
            f32x4 acc[4] = {};
#pragma unroll
            for (int fm = 0; fm < 4; ++fm) {
                acc[fm] = __builtin_amdgcn_mfma_f32_16x16x32_f16(
                    af[fm][0], bxc, acc[fm], 0, 0, 0);
                acc[fm] = __builtin_amdgcn_mfma_f32_16x16x32_f16(
                    af[fm][1], hfr[fn], acc[fm], 0, 0, 0);
            }

            int px = wn + fn * 16 + lm;
            size_t p = (size_t)(pbase + px);
            f16_t cn16[4], hn16[4];
            float part = 0.f;
#pragma unroll
            for (int r = 0; r < 4; ++r) {
                float fg = sigm(acc[0][r] + bf4[r]);
                float ig = sigm(acc[1][r] + bi4[r]);
                float og = sigm(acc[2][r] + bo4[r]);
                float gg = sigm(acc[3][r] + bc4[r]);
                float cn = fg * (float)cold[fn][r] + ig * gg;
                cn16[r] = (f16_t)cn;
                hn16[r] = (f16_t)(og * sigm(cn));
                part = fmaf(cn, wo[r], part);
            }
            if (!last) {
                *(uint2*)&c[p * 32 + o0] = *(const uint2*)cn16;
                *(uint2*)&h[p * 32 + o0] = *(const uint2*)hn16;
            }
            part += __shfl_xor(part, 16, 64);
            part += __shfl_xor(part, 32, 64);
            if (quad == 0) red[tb][px * 2 + (wm >> 6)] = part;
        }

        __syncthreads();   // sB[tb^1], red[tb] visible; sC[tb] staging drained

        // rotate prefetched h/c into current
#pragma unroll
        for (int fn = 0; fn < 4; ++fn) {
            hfr[fn] = hfr2[fn];
#pragma unroll
            for (int r = 0; r < 4; ++r) cold[fn][r] = cold2[fn][r];
        }
    }
    tail(5);
}

// ---------------------------------------------------------------------------
extern "C" void kernel_launch(void* const* d_in, const int* in_sizes, int n_in,
                              void* d_out, int out_size, void* d_ws, size_t ws_size,
                              hipStream_t stream)
{
    const float* x_in  = (const float*)d_in[0];
    const float* Lrow  = (const float*)d_in[1];
    const float* Lcol  = (const float*)d_in[2];
    const float* theta = (const float*)d_in[3];
    const float* bias  = (const float*)d_in[4];
    const float* Wf = (const float*)d_in[5];
    const float* Uf = (const float*)d_in[6];
    const float* bf = (const float*)d_in[7];
    const float* Wi = (const float*)d_in[8];
    const float* Ui = (const float*)d_in[9];
    const float* bi = (const float*)d_in[10];
    const float* Wo = (const float*)d_in[11];
    const float* Uo = (const float*)d_in[12];
    const float* bo = (const float*)d_in[13];
    const float* Wc = (const float*)d_in[14];
    const float* Uc = (const float*)d_in[15];
    const float* bc = (const float*)d_in[16];
    const float* Wout = (const float*)d_in[17];
    const float* bout = (const float*)d_in[18];
    (void)in_sizes; (void)n_in; (void)out_size;

    float* out = (float*)d_out;   // working x buffer

    // ---- workspace pool (136.9 MB) ----
    f16_t* base = (f16_t*)d_ws;
    f16_t* Cbf  = base;                              // 14,745,600 f16
    f16_t* h    = Cbf + 14745600;                    // 18,874,368 f16
    f16_t* c    = h + 18874368;                      // 18,874,368 f16
    f16_t* S0   = c + 18874368;                      // 2*STK (Tr | Tc)
    f16_t* S1   = S0 + 2 * STK;
    f16_t* XR0  = S1 + 2 * STK;                      // STK (single level)
    f16_t* Wstack  = XR0 + STK;                      // 8192
    f16_t* thstack = Wstack + 8192;                  // 1024
    f16_t* xT0  = thstack + 1024;                    // MXK
    f16_t* xT1  = xT0 + MXK;                         // MXK
    if (ws_size < (size_t)136857600) return;

    hipMemcpyAsync(out, x_in, (size_t)MXK * 4, hipMemcpyDeviceToDevice, stream);

    prep_gate<<<36, 256, 0, stream>>>(Wf, Wi, Wo, Wc, Uf, Ui, Uo, Uc, theta,
                                      bias, Wstack, thstack);
    init_split<<<MXK / 256, 256, 0, stream>>>(Lrow, Lcol, S0, S1);
    // T2 = 2*L@L - T0 (Tr+Tc dual stack): A = L hi, B = L dual
    gemm_bt_h2<<<96, 256, 0, stream>>>(
        S0 + MXK, S0 + MXK, S1 + MXK, S0, S1,
        S0 + 2 * MXK, S1 + 2 * MXK, nullptr,
        DIM, DIM, 2, 8, STK, 0);
    // T3 = 2*L@T2 - T1  AND  T4 = 2*T2@T2 - T0, both stacks, one launch
    gemm_bt_h2<<<192, 256, 0, stream>>>(
        S0, S0, S1, S0, S1, S0, S1, nullptr,
        DIM, DIM, 4, 8, STK, 0);

    for (int it = 0; it < 3; ++it) {
        // xT dual split + x f16 into XR rows 0..767 + Cbf rows 0..767 (j0)
        transpose_cvt2x<<<dim3(24, 24), 256, 0, stream>>>(out, xT0, xT1,
                                                          XR0, Cbf);
        // stage1: XR rows 768..3839 = T_{1..4} @ x; SINGLE-product (R29):
        // A is T_hi only (S1 never read here) and XR stored f16, so the
        // dual-B term is one of three comparable 2^-11 error terms
        gemm_bt_h2<<<192, 256, 0, stream>>>(
            S0 + MXK, xT0, nullptr,
            nullptr, nullptr,
            XR0 + MXK, nullptr, Cbf + (size_t)DIM * 3840,
            DIM, DIM, 1, 8, 0, 0);
        // stage2: Cbf cols 768.. = XR @ Tc_{1..4}^T (M=3840, N=3072, K=768)
        // single-product (B2 = nullptr, R20)
        gemm_bt_h2<<<960, 256, 0, stream>>>(
            XR0, S0 + STK + MXK, nullptr,
            nullptr, nullptr,
            Cbf, nullptr, nullptr, DIM, 3840, 3, 32, 0, DIM);
        // gates: theta-MFMA + gate-MFMA + LSTM + x += tanh(c.Wout+b)
        gate_theta_mfma<<<768, 256, 0, stream>>>(
            Cbf, thstack, Wstack,
            bf, bi, bo, bc, Wout, bout, h, c, out,
            it == 0 ? 1 : 0, it == 2 ? 1 : 0);
    }
}

// Round 15
// 415.547 us; speedup vs baseline: 1.6880x; 1.0120x over previous
//
#include <hip/hip_runtime.h>
#include <hip/hip_bf16.h>
#include <stdint.h>

// ---------------------------------------------------------------------------
// MGCNN on MI355X — f16 MFMA conv + all-f16 MFMA gate kernel.
//
// Number format history: B operands were dual-level (b = b1 + b2, unscaled
// residual, shared f32 accumulator). R20/R29 dropped dual-B in stage2 and
// stage1 (A hi-only + f16-stored outputs make the B residual term sub-
// rounding); R30 drops it in the cheb recursion too — the recursion's A
// side has ALWAYS been hi-only, so B-dual removed only one of two
// symmetric eps terms; consumers read hi parts only. Dual storage (S1)
// retained for the T0/T1 epilogue subtraction terms.
//
// R30: dead-code + cheb single-product. (1) transpose no longer computes
// or writes xT1 (dead since R29's stage1 single-product). (2) T2 and
// T3/T4 launches pass B2=nullptr: halves their MFMAs; these 96/192-block
// launches are latency-bound at <1 block/CU, expect ~25-35% dur cut.
// Gate = R25 plateau config (45.4 us, 7 structural attacks falsified).
// GEMMs keep R25's XCD swizzle. absmax risk: 0.0156 -> <=0.031.
// ---------------------------------------------------------------------------

#define DIM 768
#define MXK 589824        // 768*768
#define STK 2949120       // 5*768*768

typedef _Float16 f16x8 __attribute__((ext_vector_type(8)));
typedef float f32x4 __attribute__((ext_vector_type(4)));
typedef unsigned short ushort_t;
typedef _Float16 f16_t;

__device__ __forceinline__ float sigm(float v) {
    float e = __expf(-v);
    return __builtin_amdgcn_rcpf(1.0f + e);   // raw v_rcp_f32, ~1 ulp
}
__device__ __forceinline__ void split2h(float f, f16_t& h1, f16_t& h2) {
    h1 = (f16_t)f;
    h2 = (f16_t)(f - (float)h1);   // unscaled residual (shared-acc scheme)
}

// async 16B global->LDS (LDS dest = wave-uniform base + lane*16)
__device__ __forceinline__ void gl_lds16(const f16_t* g, f16_t* l) {
    auto gp = reinterpret_cast<const __attribute__((address_space(1))) uint32_t*>(
        reinterpret_cast<uintptr_t>(g));
    auto lp = reinterpret_cast<__attribute__((address_space(3))) uint32_t*>(
        reinterpret_cast<uintptr_t>(l));
    __builtin_amdgcn_global_load_lds(gp, lp, 16, 0, 0);
}

// ---------------------------------------------------------------------------
// init: T0 = I, T1 = L  ->  f16x2s, Tr stack then Tc stack per level
// ---------------------------------------------------------------------------
__global__ __launch_bounds__(256) void init_split(
    const float* __restrict__ Lrow, const float* __restrict__ Lcol,
    f16_t* __restrict__ S0, f16_t* __restrict__ S1)
{
    int idx = blockIdx.x * 256 + threadIdx.x;
    int p = idx / DIM, m = idx % DIM;
    f16_t eye = (p == m) ? (f16_t)1.0f : (f16_t)0.0f;
    S0[idx] = eye; S1[idx] = (f16_t)0.0f;
    S0[STK + idx] = eye; S1[STK + idx] = (f16_t)0.0f;
    f16_t h1, h2;
    split2h(Lrow[idx], h1, h2);
    S0[MXK + idx] = h1; S1[MXK + idx] = h2;
    split2h(Lcol[idx], h1, h2);
    S0[STK + MXK + idx] = h1; S1[STK + MXK + idx] = h2;
}

// ---------------------------------------------------------------------------
// prep: Wstack f16 [128 R][64 k] and thstack f16 [32 o][32 k=ij]
// (k=25 -> bias row, pairs with the ones-row staged into sC; k>25 -> 0)
// ---------------------------------------------------------------------------
__global__ __launch_bounds__(256) void prep_gate(
    const float* __restrict__ Wf, const float* __restrict__ Wi,
    const float* __restrict__ Wo, const float* __restrict__ Wc,
    const float* __restrict__ Uf, const float* __restrict__ Ui,
    const float* __restrict__ Uo, const float* __restrict__ Uc,
    const float* __restrict__ theta, const float* __restrict__ biasv,
    f16_t* __restrict__ Wstack, f16_t* __restrict__ thstack)
{
    int idx = blockIdx.x * 256 + threadIdx.x;
    if (idx < 8192) {
        int R = idx >> 6, k = idx & 63;
        int g = (R >> 4) & 3, o = (R >> 6) * 16 + (R & 15);
        const float* Wg[4] = {Wf, Wi, Wo, Wc};
        const float* Ug[4] = {Uf, Ui, Uo, Uc};
        float v = (k < 32) ? Wg[g][k * 32 + o] : Ug[g][(k - 32) * 32 + o];
        Wstack[idx] = (f16_t)v;
    } else if (idx < 9216) {
        int t = idx - 8192;
        int o = t >> 5, k = t & 31;
        float v = (k < 25) ? theta[k * 32 + o]
                           : (k == 25 ? biasv[o] : 0.0f);
        thstack[o * 32 + k] = (f16_t)v;
    }
}

// ---------------------------------------------------------------------------
// transpose 768x768: xT0[q][p] = (f16)x[p][q] (single, B of stage1 — xT1
// residual dead since R29); straight f16 into XR rows 0..767 (A of stage2,
// T_0 = I) and Cbf rows 0..767 cols 0..767 (T_0 = I both sides).
// ---------------------------------------------------------------------------
__global__ __launch_bounds__(256) void transpose_cvt2x(
    const float* __restrict__ in, f16_t* __restrict__ o1,
    f16_t* __restrict__ xr0, f16_t* __restrict__ Cbf)
{
    __shared__ float t[32][33];
    int x = threadIdx.x & 31, y = threadIdx.x >> 5;
    int bx = blockIdx.x * 32, by = blockIdx.y * 32;
#pragma unroll
    for (int r = 0; r < 4; ++r) {
        int p = by + y + 8 * r, q = bx + x;
        size_t oi = (size_t)p * DIM + q;
        float v = in[oi];
        t[y + 8 * r][x] = v;
        f16_t hv = (f16_t)v;
        xr0[oi] = hv;
        Cbf[(size_t)p * 3840 + q] = hv;
    }
    __syncthreads();
#pragma unroll
    for (int r = 0; r < 4; ++r) {
        float v = t[x][y + 8 * r];
        size_t o = (size_t)(bx + y + 8 * r) * DIM + by + x;
        o1[o] = (f16_t)v;
    }
}

// ---------------------------------------------------------------------------
// f16 MFMA GEMM engine, double-buffered LDS (B-transposed, k-contig),
// 128x96 block, BK=32, 4 waves, wave tile 64x48.
// Shared accumulator (R18): acc[4][3] -> __launch_bounds__(256,4),
// 4 blocks/CU (LDS 160 KiB exactly), single scheduling round at 960 blocks.
// R20/R29/R30: B2 == nullptr -> single-product (half the MFMAs, lev-1
// staging and reads skipped). R25: XCD-aware bijective block swizzle
// (all launches have nwg%8==0) -> contiguous logical chunk per XCD.
// mode 1: f16 single out D1 (ldc) + optional D3 (ld 3840);
// mode 2: cheb T2 (v = 2*acc - P), dual out, dual stack via halfStride;
// mode 3: f16 single out (+coloff), supertile (nbx=32);
// mode 4: batched cheb T3+T4 (offset table; pass S0/S1 bases).
// ---------------------------------------------------------------------------
__global__ __launch_bounds__(256, 4) void gemm_bt_h2(
    const f16_t* __restrict__ A1,
    const f16_t* __restrict__ B1, const f16_t* __restrict__ B2,
    const f16_t* __restrict__ P1, const f16_t* __restrict__ P2,
    f16_t* __restrict__ D1, f16_t* __restrict__ D2, f16_t* __restrict__ D3,
    int K, int ldc, int mode, int nbx, int halfStride, int coloff)
{
    __shared__ __align__(16) f16_t sA[2][128 * 32];       // 2 x 8 KB
    __shared__ __align__(16) f16_t sB[2][2 * 96 * 32];    // 2 x 12 KB

    const int tid = threadIdx.x;
    const bool dual = (B2 != nullptr);

    // XCD-aware bijective swizzle (T1): blocks on one XCD (= blockIdx%8)
    // get a CONTIGUOUS chunk of logical ids, so panel reuse stays in that
    // XCD's private L2 instead of striping across all 8 XCDs.
    int g = blockIdx.x;
    {
        int nwg = gridDim.x;
        if ((nwg & 7) == 0) g = (g & 7) * (nwg >> 3) + (g >> 3);
    }

    int bx, by;
    size_t hoff = 0;
    int aoff = 0, boff = 0, poff = 0, doff = 0;
    if (mode == 3) {
        // supertile: 8 rows x 32 cols share A/B panels -> L2 reuse
        int sup = g >> 8;                   // / (8*32)
        int rows0 = sup * 8;
        int H = 30 - rows0; if (H > 8) H = 8;
        int local = g - rows0 * nbx;
        by = rows0 + local % H;
        bx = local / H;
    } else if (mode == 4) {
        // T3 = 2*L@T2 - T1 (g<96), T4 = 2*T2@T2 - T0 (g>=96); Tr|Tc stacks
        int t34 = g / 96, r = g % 96;
        int stack = r / 48, rr = r % 48;
        by = rr >> 3; bx = rr & 7;
        hoff = (size_t)stack * halfStride;
        if (t34 == 0) { aoff = MXK; boff = 2 * MXK; poff = MXK; doff = 3 * MXK; }
        else          { aoff = 2 * MXK; boff = 2 * MXK; poff = 0; doff = 4 * MXK; }
    } else {
        bx = g % nbx;
        by = g / nbx;
        if (mode == 2 && by >= 6) { by -= 6; hoff = (size_t)halfStride; }
    }
    const int m0 = by * 128, n0 = bx * 96;

    const f16_t* Asrc1 = A1 + hoff + aoff;
    const f16_t* Bsrc1 = B1 + hoff + boff;
    const f16_t* Bsrc2 = dual ? B2 + hoff + boff : nullptr;
    const f16_t* Pq1 = P1 ? P1 + hoff + poff : nullptr;
    const f16_t* Pq2 = P2 ? P2 + hoff + poff : nullptr;
    f16_t* Dq1 = D1 + hoff + doff;
    f16_t* Dq2 = D2 ? D2 + hoff + doff : nullptr;

    const int lane = tid & 63, w4 = tid >> 6;
    const int wm = (w4 & 1) * 64, wn = (w4 >> 1) * 48;
    const int lm = lane & 15, quad = lane >> 4;
    const int psw = (quad ^ ((lm >> 1) & 3)) * 8;

    // A staging: 512 16B-slots (128 rows x 4 chunks), 2 calls
    const f16_t* gApt[2]; int aslot[2];
#pragma unroll
    for (int cc = 0; cc < 2; ++cc) {
        int s = cc * 256 + w4 * 64 + lane;   // 0..511
        int row = s >> 2, pos = s & 3;
        int chunk = pos ^ ((row >> 1) & 3);
        gApt[cc] = Asrc1 + (size_t)(m0 + row) * K + chunk * 8;
        aslot[cc] = s * 8;
    }
    // B staging: dual = 768 slots (2 lev x 96 rows x 4 chunks), 3 calls;
    // single = 384 slots (lev 0 only): cc=0 full, cc=1 first 2 waves, cc=2 off
    const f16_t* gBpt[3]; int bslot[3]; bool bact[3];
#pragma unroll
    for (int cc = 0; cc < 3; ++cc) {
        int slot = cc * 256 + w4 * 64 + lane;
        bact[cc] = dual || (slot < 384);
        int lev = slot >= 384 ? 1 : 0;
        int s = slot - lev * 384;
        int row = s >> 2, pos = s & 3;
        int chunk = pos ^ ((row >> 1) & 3);
        const f16_t* bs = (lev && dual) ? Bsrc2 : Bsrc1;
        gBpt[cc] = bs + (size_t)(n0 + row) * K + chunk * 8;
        bslot[cc] = lev * 3072 + s * 8;
    }

    f32x4 acc[4][3] = {};

    // preload K-chunk 0 into buffer 0
#pragma unroll
    for (int cc = 0; cc < 2; ++cc) gl_lds16(gApt[cc], &sA[0][aslot[cc]]);
#pragma unroll
    for (int cc = 0; cc < 3; ++cc)
        if (bact[cc]) gl_lds16(gBpt[cc], &sB[0][bslot[cc]]);
    __syncthreads();

    int ib = 0;
    for (int kb = 0; kb < K; kb += 32, ib ^= 1) {
        // prefetch next chunk into the other buffer (overlaps MFMA below)
        if (kb + 32 < K) {
            int nb = ib ^ 1;
#pragma unroll
            for (int cc = 0; cc < 2; ++cc)
                gl_lds16(gApt[cc] + kb + 32, &sA[nb][aslot[cc]]);
#pragma unroll
            for (int cc = 0; cc < 3; ++cc)
                if (bact[cc]) gl_lds16(gBpt[cc] + kb + 32, &sB[nb][bslot[cc]]);
        }

        f16x8 bfr[2][3];
#pragma unroll
        for (int fn = 0; fn < 3; ++fn)
            bfr[0][fn] = *(const f16x8*)&sB[ib][(wn + fn * 16 + lm) * 32 + psw];
        if (dual) {
#pragma unroll
            for (int fn = 0; fn < 3; ++fn)
                bfr[1][fn] = *(const f16x8*)&sB[ib][3072 +
                                                (wn + fn * 16 + lm) * 32 + psw];
        }
#pragma unroll
        for (int fm = 0; fm < 4; ++fm) {
            f16x8 a1v = *(const f16x8*)&sA[ib][(wm + fm * 16 + lm) * 32 + psw];
#pragma unroll
            for (int fn = 0; fn < 3; ++fn) {
                acc[fm][fn] = __builtin_amdgcn_mfma_f32_16x16x32_f16(
                    a1v, bfr[0][fn], acc[fm][fn], 0, 0, 0);
                if (dual)
                    acc[fm][fn] = __builtin_amdgcn_mfma_f32_16x16x32_f16(
                        a1v, bfr[1][fn], acc[fm][fn], 0, 0, 0);
            }
        }
        // barrier: (a) all waves done reading buf ib (safe to overwrite at
        // kb+64), (b) vmcnt(0) drain -> buf ib^1 staged (loads overlapped
        // the MFMA section above)
        __syncthreads();
    }

    // epilogue: C/D layout col=lane&15, row=quad*4+reg  [verified m89/m91]
#pragma unroll
    for (int fm = 0; fm < 4; ++fm)
#pragma unroll
        for (int fn = 0; fn < 3; ++fn) {
            int col = n0 + wn + fn * 16 + lm;
#pragma unroll
            for (int r = 0; r < 4; ++r) {
                int row = m0 + wm + fm * 16 + quad * 4 + r;
                float val = acc[fm][fn][r];
                if (mode == 3) {
                    Dq1[(size_t)row * ldc + coloff + col] = (f16_t)val;
                } else if (mode == 1) {
                    Dq1[(size_t)row * ldc + col] = (f16_t)val;
                    if (D3) D3[(size_t)row * 3840 + col] = (f16_t)val;
                } else {
                    size_t o = (size_t)row * ldc + col;
                    val = 2.0f * val - ((float)Pq1[o] + (float)Pq2[o]);
                    f16_t h1, h2;
                    split2h(val, h1, h2);
                    Dq1[o] = h1; Dq2[o] = h2;
                }
            }
        }
}

// ---------------------------------------------------------------------------
// Gate kernel (all f16). R25 plateau config (declared best: 45.4 us/disp,
// 7 structural variants falsified). Grid 768, single-barrier pipeline.
// Per phase t:
//   tail(t-1) | stage(t+2)->sC[t&1] | theta(t+1): sC[(t+1)&1]->sB[(t+1)&1]
//   | h/c prefetch(t+1) | gate(t): sB[t&1]+hfr -> h/c stores, red[t&1]
//   | barrier
// ---------------------------------------------------------------------------
__global__ __launch_bounds__(256, 3) void gate_theta_mfma(
    const f16_t* __restrict__ Cbf, const f16_t* __restrict__ thstack,
    const f16_t* __restrict__ Wstack,
    const float* __restrict__ bfv, const float* __restrict__ biv,
    const float* __restrict__ bov, const float* __restrict__ bcv,
    const float* __restrict__ Wout, const float* __restrict__ bout,
    f16_t* __restrict__ h, f16_t* __restrict__ c, float* __restrict__ x,
    int first, int last)
{
    __shared__ __align__(16) ushort_t sC[2][26 * 128];  // 2 x 6.5 KB
    __shared__ __align__(16) ushort_t sB[2][128 * 40];  // 2 x 10 KB
    __shared__ float red[2][256];                       // 2 KB

    const int tid = threadIdx.x;
    const int lane = tid & 63, w4 = tid >> 6;
    const int wm = (w4 & 1) * 64, wn = (w4 >> 1) * 64;
    const int lm = lane & 15, quad = lane >> 4;
    const int m = blockIdx.x;
    const int o0 = (wm >> 2) + quad * 4;
    const int pw = w4 * 32;

    // ones rows (bias-via-MFMA) once into both buffers
    if (tid < 32) {
        uint4 ones;
        ones.x = ones.y = ones.z = ones.w = 0x3C003C00u;  // f16 1.0 x2
        *(uint4*)&sC[tid >> 4][25 * 128 + (tid & 15) * 8] = ones;
    }

    // stage tile with first col n0 -> sC[buf] rows 0..24 (async, 400 x 16B)
    auto stage = [&](int n0, int buf) {
#pragma unroll
        for (int cc = 0; cc < 2; ++cc) {
            int s = cc * 256 + tid;
            if (s < 400) {
                int ij = s >> 4, f = s & 15;
                int i5 = (ij * 205) >> 10;       // ij/5 for ij<32
                int j5 = ij - i5 * 5;
                size_t ga = (size_t)(i5 * DIM + m) * 3840 + j5 * DIM + n0 + f * 8;
                gl_lds16(&Cbf[ga], (f16_t*)&sC[buf][ij * 128 + f * 8]);
            }
        }
    };

    // uniform operands, once per block
    f16x8 bth[2];
#pragma unroll
    for (int fn = 0; fn < 2; ++fn)
        bth[fn] = *(const f16x8*)&thstack[(fn * 16 + lm) * 32 + quad * 8];
    f16x8 af[4][2];
#pragma unroll
    for (int fm = 0; fm < 4; ++fm)
#pragma unroll
        for (int kc = 0; kc < 2; ++kc)
            af[fm][kc] = *(const f16x8*)&Wstack[(wm + fm * 16 + lm) * 64 +
                                                kc * 32 + quad * 8];
    const float4 bgf = *(const float4*)&bfv[o0];
    const float4 bgi = *(const float4*)&biv[o0];
    const float4 bgo = *(const float4*)&bov[o0];
    const float4 bgc = *(const float4*)&bcv[o0];
    const float4 wo4 = *(const float4*)&Wout[o0];
    float bf4[4] = {bgf.x, bgf.y, bgf.z, bgf.w};
    float bi4[4] = {bgi.x, bgi.y, bgi.z, bgi.w};
    float bo4[4] = {bgo.x, bgo.y, bgo.z, bgo.w};
    float bc4[4] = {bgc.x, bgc.y, bgc.z, bgc.w};
    float wo[4] = {wo4.x, wo4.y, wo4.z, wo4.w};
    const float bout0 = bout[0];

    // theta phase: read sC[sbuf], write xc into sB[dbuf]
    auto theta = [&](int sbuf, int dbuf) {
        const f16_t* sCf = (const f16_t*)sC[sbuf];
        f32x4 tacc[2][2] = {};
        f16x8 a0, a1;
#pragma unroll
        for (int j = 0; j < 8; ++j) {
            int k = quad * 8 + j;
            int ij = k > 25 ? 25 : k;   // k>25 hits ones row x thstack 0
            a0[j] = sCf[ij * 128 + pw + lm];
            a1[j] = sCf[ij * 128 + pw + 16 + lm];
        }
#pragma unroll
        for (int fn = 0; fn < 2; ++fn) {
            tacc[0][fn] = __builtin_amdgcn_mfma_f32_16x16x32_f16(
                a0, bth[fn], tacc[0][fn], 0, 0, 0);
            tacc[1][fn] = __builtin_amdgcn_mfma_f32_16x16x32_f16(
                a1, bth[fn], tacc[1][fn], 0, 0, 0);
        }
#pragma unroll
        for (int fm2 = 0; fm2 < 2; ++fm2)
#pragma unroll
            for (int fn = 0; fn < 2; ++fn)
#pragma unroll
                for (int r = 0; r < 4; ++r) {
                    f16_t hv = (f16_t)tacc[fm2][fn][r];
                    sB[dbuf][(pw + fm2 * 16 + quad * 4 + r) * 40 +
                             fn * 16 + lm] = __builtin_bit_cast(ushort_t, hv);
                }
    };

    // x-tail for tile t (reads red[t&1]); call AFTER the barrier of phase t
    auto tail = [&](int t) {
        if (tid < 128) {
            float v = red[t & 1][tid * 2] + red[t & 1][tid * 2 + 1] + bout0;
            v = fminf(fmaxf(v, -15.f), 15.f);
            float e = __expf(2.f * v);
            x[m * DIM + t * 128 + tid] +=
                (e - 1.f) * __builtin_amdgcn_rcpf(e + 1.f);
        }
    };

    // prologue: stage tiles 0 and 1, load tile-0 h/c
    stage(0, 0);
    stage(128, 1);
    f16x8 hfr[4];
    f16_t cold[4][4];
    if (!first) {
#pragma unroll
        for (int fn = 0; fn < 4; ++fn) {
            size_t p = (size_t)(m * DIM + wn + fn * 16 + lm);
            hfr[fn] = *(const f16x8*)&h[p * 32 + quad * 8];
            *(uint2*)cold[fn] = *(const uint2*)&c[p * 32 + o0];
        }
    } else {
#pragma unroll
        for (int fn = 0; fn < 4; ++fn) {
#pragma unroll
            for (int j = 0; j < 8; ++j) hfr[fn][j] = (f16_t)0.0f;
#pragma unroll
            for (int r = 0; r < 4; ++r) cold[fn][r] = (f16_t)0.0f;
        }
    }
    __syncthreads();   // ones + tiles 0,1 staged
    theta(0, 0);
    __syncthreads();   // sB[0] visible

    for (int t = 0; t < 6; ++t) {
        const int tb = t & 1;
        const int pbase = m * DIM + t * 128;

        // tail of previous tile (red[(t-1)&1] made visible by last barrier)
        if (t > 0) tail(t - 1);

        // stage 2 tiles ahead into sC[tb] (read by theta(t+2) next phase)
        if (t + 2 < 6) stage((t + 2) * 128, tb);

        // theta for next tile into sB[tb^1]
        if (t + 1 < 6) theta(tb ^ 1, tb ^ 1);

        // h/c prefetch for next tile
        f16x8 hfr2[4];
        f16_t cold2[4][4];
        if (t + 1 < 6 && !first) {
#pragma unroll
            for (int fn = 0; fn < 4; ++fn) {
                size_t p = (size_t)(pbase + 128 + wn + fn * 16 + lm);
                hfr2[fn] = *(const f16x8*)&h[p * 32 + quad * 8];
                *(uint2*)cold2[fn] = *(const uint2*)&c[p * 32 + o0];
            }
        } else {
#pragma unroll
            for (int fn = 0; fn < 4; ++fn) {
#pragma unroll
                for (int j = 0; j < 8; ++j) hfr2[fn][j] = (f16_t)0.0f;
#pragma unroll
                for (int r = 0; r < 4; ++r) cold2[fn][r] = (f16_t)0.0f;
            }
        }

        // gate for tile t
#pragma unroll
        for (int fn = 0; fn < 4; ++fn) {
            f16x8 bxc = *(const f16x8*)&sB[tb][(wn + fn * 16 + lm) * 40 +
                                              quad * 8];
            f32x4 acc[4] = {};
#pragma unroll
            for (int fm = 0; fm < 4; ++fm) {
                acc[fm] = __builtin_amdgcn_mfma_f32_16x16x32_f16(
                    af[fm][0], bxc, acc[fm], 0, 0, 0);
                acc[fm] = __builtin_amdgcn_mfma_f32_16x16x32_f16(
                    af[fm][1], hfr[fn], acc[fm], 0, 0, 0);
            }

            int px = wn + fn * 16 + lm;
            size_t p = (size_t)(pbase + px);
            f16_t cn16[4], hn16[4];
            float part = 0.f;
#pragma unroll
            for (int r = 0; r < 4; ++r) {
                float fg = sigm(acc[0][r] + bf4[r]);
                float ig = sigm(acc[1][r] + bi4[r]);
                float og = sigm(acc[2][r] + bo4[r]);
                float gg = sigm(acc[3][r] + bc4[r]);
                float cn = fg * (float)cold[fn][r] + ig * gg;
                cn16[r] = (f16_t)cn;
                hn16[r] = (f16_t)(og * sigm(cn));
                part = fmaf(cn, wo[r], part);
            }
            if (!last) {
                *(uint2*)&c[p * 32 + o0] = *(const uint2*)cn16;
                *(uint2*)&h[p * 32 + o0] = *(const uint2*)hn16;
            }
            part += __shfl_xor(part, 16, 64);
            part += __shfl_xor(part, 32, 64);
            if (quad == 0) red[tb][px * 2 + (wm >> 6)] = part;
        }

        __syncthreads();   // sB[tb^1], red[tb] visible; sC[tb] staging drained

        // rotate prefetched h/c into current
#pragma unroll
        for (int fn = 0; fn < 4; ++fn) {
            hfr[fn] = hfr2[fn];
#pragma unroll
            for (int r = 0; r < 4; ++r) cold[fn][r] = cold2[fn][r];
        }
    }
    tail(5);
}

// ---------------------------------------------------------------------------
extern "C" void kernel_launch(void* const* d_in, const int* in_sizes, int n_in,
                              void* d_out, int out_size, void* d_ws, size_t ws_size,
                              hipStream_t stream)
{
    const float* x_in  = (const float*)d_in[0];
    const float* Lrow  = (const float*)d_in[1];
    const float* Lcol  = (const float*)d_in[2];
    const float* theta = (const float*)d_in[3];
    const float* bias  = (const float*)d_in[4];
    const float* Wf = (const float*)d_in[5];
    const float* Uf = (const float*)d_in[6];
    const float* bf = (const float*)d_in[7];
    const float* Wi = (const float*)d_in[8];
    const float* Ui = (const float*)d_in[9];
    const float* bi = (const float*)d_in[10];
    const float* Wo = (const float*)d_in[11];
    const float* Uo = (const float*)d_in[12];
    const float* bo = (const float*)d_in[13];
    const float* Wc = (const float*)d_in[14];
    const float* Uc = (const float*)d_in[15];
    const float* bc = (const float*)d_in[16];
    const float* Wout = (const float*)d_in[17];
    const float* bout = (const float*)d_in[18];
    (void)in_sizes; (void)n_in; (void)out_size;

    float* out = (float*)d_out;   // working x buffer

    // ---- workspace pool (136.9 MB) ----
    f16_t* base = (f16_t*)d_ws;
    f16_t* Cbf  = base;                              // 14,745,600 f16
    f16_t* h    = Cbf + 14745600;                    // 18,874,368 f16
    f16_t* c    = h + 18874368;                      // 18,874,368 f16
    f16_t* S0   = c + 18874368;                      // 2*STK (Tr | Tc)
    f16_t* S1   = S0 + 2 * STK;
    f16_t* XR0  = S1 + 2 * STK;                      // STK (single level)
    f16_t* Wstack  = XR0 + STK;                      // 8192
    f16_t* thstack = Wstack + 8192;                  // 1024
    f16_t* xT0  = thstack + 1024;                    // MXK
    f16_t* xT1  = xT0 + MXK;                         // MXK (unused since R29)
    (void)xT1;
    if (ws_size < (size_t)136857600) return;

    hipMemcpyAsync(out, x_in, (size_t)MXK * 4, hipMemcpyDeviceToDevice, stream);

    prep_gate<<<36, 256, 0, stream>>>(Wf, Wi, Wo, Wc, Uf, Ui, Uo, Uc, theta,
                                      bias, Wstack, thstack);
    init_split<<<MXK / 256, 256, 0, stream>>>(Lrow, Lcol, S0, S1);
    // T2 = 2*L@L - T0 (Tr+Tc dual-stored): single-product (R30; A was
    // always hi-only so B residual was one of two symmetric eps terms)
    gemm_bt_h2<<<96, 256, 0, stream>>>(
        S0 + MXK, S0 + MXK, nullptr, S0, S1,
        S0 + 2 * MXK, S1 + 2 * MXK, nullptr,
        DIM, DIM, 2, 8, STK, 0);
    // T3 = 2*L@T2 - T1  AND  T4 = 2*T2@T2 - T0, single-product (R30)
    gemm_bt_h2<<<192, 256, 0, stream>>>(
        S0, S0, nullptr, S0, S1, S0, S1, nullptr,
        DIM, DIM, 4, 8, STK, 0);

    for (int it = 0; it < 3; ++it) {
        // xT0 = x^T f16 + x f16 into XR rows 0..767 + Cbf rows 0..767 (j0)
        transpose_cvt2x<<<dim3(24, 24), 256, 0, stream>>>(out, xT0,
                                                          XR0, Cbf);
        // stage1: XR rows 768..3839 = T_{1..4} @ x; single-product (R29)
        gemm_bt_h2<<<192, 256, 0, stream>>>(
            S0 + MXK, xT0, nullptr,
            nullptr, nullptr,
            XR0 + MXK, nullptr, Cbf + (size_t)DIM * 3840,
            DIM, DIM, 1, 8, 0, 0);
        // stage2: Cbf cols 768.. = XR @ Tc_{1..4}^T (M=3840, N=3072, K=768)
        // single-product (R20)
        gemm_bt_h2<<<960, 256, 0, stream>>>(
            XR0, S0 + STK + MXK, nullptr,
            nullptr, nullptr,
            Cbf, nullptr, nullptr, DIM, 3840, 3, 32, 0, DIM);
        // gates: theta-MFMA + gate-MFMA + LSTM + x += tanh(c.Wout+b)
        gate_theta_mfma<<<768, 256, 0, stream>>>(
            Cbf, thstack, Wstack,
            bf, bi, bo, bc, Wout, bout, h, c, out,
            it == 0 ? 1 : 0, it == 2 ? 1 : 0);
    }
}